// Round 1
// baseline (11076.131 us; speedup 1.0000x reference)
//
#include <hip/hip_runtime.h>
#include <math.h>

#define EPSF 1e-5f

// ===================== generic tiled fp32 GEMM =====================
// C[m,n] = sum_k A[m,k]*B(k,n)  (+bias[n]) (+res[m,n]) (relu)
// TRANSB: B stored [N,K] (row-major), else [K,N].
// Batched via blockIdx.z = z1*Z2+z2 with per-component element strides.
template<bool TRANSB, bool RELU, bool BIAS, bool RES>
__global__ __launch_bounds__(256) void gemm_k(
    const float* __restrict__ A, const float* __restrict__ Bm,
    const float* __restrict__ bias, const float* __restrict__ res,
    float* __restrict__ C,
    int M, int N, int K, int lda, int ldb, int ldc,
    int Z2, long long sAz1, long long sAz2, long long sBz1, long long sBz2,
    long long sCz1, long long sCz2)
{
    int z = blockIdx.z;
    int z1 = z / Z2, z2 = z - z1 * Z2;
    A  += z1 * sAz1 + z2 * sAz2;
    Bm += z1 * sBz1 + z2 * sBz2;
    C  += z1 * sCz1 + z2 * sCz2;
    const float* resp = nullptr;
    if (RES) resp = res + z1 * sCz1 + z2 * sCz2;

    __shared__ float As[16][68];
    __shared__ float Bs[16][68];
    int tid = threadIdx.x;
    int tx = tid & 15, ty = tid >> 4;
    int m0 = blockIdx.y * 64, n0 = blockIdx.x * 64;
    float acc[4][4] = {};

    for (int kt = 0; kt < K; kt += 16) {
#pragma unroll
        for (int e = 0; e < 4; e++) {
            int flat = tid + e * 256;
            int k = flat & 15, m = flat >> 4;
            As[k][m] = A[(size_t)(m0 + m) * lda + (kt + k)];
        }
#pragma unroll
        for (int e = 0; e < 4; e++) {
            int flat = tid + e * 256;
            if (TRANSB) {
                int k = flat & 15, n = flat >> 4;
                Bs[k][n] = (n0 + n < N) ? Bm[(size_t)(n0 + n) * ldb + (kt + k)] : 0.f;
            } else {
                int n = flat & 63, k = flat >> 6;
                Bs[k][n] = (n0 + n < N) ? Bm[(size_t)(kt + k) * ldb + (n0 + n)] : 0.f;
            }
        }
        __syncthreads();
#pragma unroll
        for (int k = 0; k < 16; k++) {
            float a[4], b[4];
#pragma unroll
            for (int i = 0; i < 4; i++) a[i] = As[k][ty * 4 + i];
#pragma unroll
            for (int j = 0; j < 4; j++) b[j] = Bs[k][tx * 4 + j];
#pragma unroll
            for (int i = 0; i < 4; i++)
#pragma unroll
                for (int j = 0; j < 4; j++)
                    acc[i][j] = fmaf(a[i], b[j], acc[i][j]);
        }
        __syncthreads();
    }
#pragma unroll
    for (int i = 0; i < 4; i++) {
        int m = m0 + ty * 4 + i;
#pragma unroll
        for (int j = 0; j < 4; j++) {
            int n = n0 + tx * 4 + j;
            if (n < N) {
                float v = acc[i][j];
                if (BIAS) v += bias[n];
                if (RES)  v += resp[(size_t)m * ldc + n];
                if (RELU) v = fmaxf(v, 0.f);
                C[(size_t)m * ldc + n] = v;
            }
        }
    }
}

// ===================== implicit-GEMM conv1d (IC=OC=768) =====================
// out[b,o,t] = relu?( bn( sum_{i,k} w[o,i,k]*in[b,i,t*stride+k-pad] + cbias[o] ) + res[b,o,t] )
// bn params laid out [4,768] = g,be,m,v.
__global__ __launch_bounds__(256) void convgemm_k(
    const float* __restrict__ in, const float* __restrict__ w,
    const float* __restrict__ cbias, const float* __restrict__ bn,
    const float* __restrict__ res, float* __restrict__ out,
    int Tin, int Tout, int KW, int stride, int pad, int dorelu)
{
    __shared__ float Ws[16][68];
    __shared__ float Is[16][68];
    int b = blockIdx.z;
    int o0 = blockIdx.y * 64, t0 = blockIdx.x * 64;
    int tid = threadIdx.x, tx = tid & 15, ty = tid >> 4;
    const float* inb = in + (size_t)b * 768 * Tin;
    int KK = 768 * KW;
    float acc[4][4] = {};

    for (int kt = 0; kt < KK; kt += 16) {
#pragma unroll
        for (int e = 0; e < 4; e++) {
            int flat = tid + e * 256;
            int k = flat & 15, o = flat >> 4;
            Ws[k][o] = w[(size_t)(o0 + o) * KK + (kt + k)];
        }
#pragma unroll
        for (int e = 0; e < 4; e++) {
            int flat = tid + e * 256;
            int kk = flat >> 6, t = flat & 63;
            int kidx = kt + kk;
            int ic, kq;
            if (KW == 1) { ic = kidx; kq = 0; }
            else         { ic = kidx / 3; kq = kidx - ic * 3; }
            int pos = (t0 + t) * stride + kq - pad;
            Is[kk][t] = ((unsigned)pos < (unsigned)Tin) ? inb[(size_t)ic * Tin + pos] : 0.f;
        }
        __syncthreads();
#pragma unroll
        for (int k = 0; k < 16; k++) {
            float a[4], bb[4];
#pragma unroll
            for (int i = 0; i < 4; i++) a[i] = Ws[k][ty * 4 + i];
#pragma unroll
            for (int j = 0; j < 4; j++) bb[j] = Is[k][tx * 4 + j];
#pragma unroll
            for (int i = 0; i < 4; i++)
#pragma unroll
                for (int j = 0; j < 4; j++)
                    acc[i][j] = fmaf(a[i], bb[j], acc[i][j]);
        }
        __syncthreads();
    }
#pragma unroll
    for (int i = 0; i < 4; i++) {
        int o = o0 + ty * 4 + i;
        float g = bn[o], be = bn[768 + o], mm = bn[1536 + o], vv = bn[2304 + o];
        float cb = cbias[o];
        float sc = g * rsqrtf(vv + EPSF);
        float sh = (cb - mm) * sc + be;
#pragma unroll
        for (int j = 0; j < 4; j++) {
            int t = t0 + tx * 4 + j;
            float val = acc[i][j] * sc + sh;
            if (res) val += res[((size_t)b * 768 + o) * Tout + t];
            if (dorelu) val = fmaxf(val, 0.f);
            out[((size_t)b * 768 + o) * Tout + t] = val;
        }
    }
}

// ===================== resblock1 front (CIN=8): conv1+bn+relu and convr+bn =====================
__global__ __launch_bounds__(256) void rb1_front_k(
    const float* __restrict__ xr, const float* __restrict__ c1w, const float* __restrict__ c1b,
    const float* __restrict__ bn1, const float* __restrict__ rw, const float* __restrict__ rbb,
    const float* __restrict__ bnr, float* __restrict__ h1, float* __restrict__ res1)
{
    int b = blockIdx.z;
    int t = blockIdx.x * 64 + (threadIdx.x & 63);
    int o = blockIdx.y * 4 + (threadIdx.x >> 6);
    const float* xb = xr + (size_t)b * 4096 * 8;

    float conv = c1b[o];
#pragma unroll
    for (int k = 0; k < 3; k++) {
        int pos = 2 * t + k - 1;
        if ((unsigned)pos < 4096u) {
            const float* xp = xb + (size_t)pos * 8;
            const float* wp = c1w + (size_t)o * 24 + k;  // w[o][c][k]
#pragma unroll
            for (int c = 0; c < 8; c++) conv += wp[c * 3] * xp[c];
        }
    }
    {
        float g = bn1[o], be = bn1[768 + o], m = bn1[1536 + o], v = bn1[2304 + o];
        float sc = g * rsqrtf(v + EPSF);
        h1[((size_t)b * 768 + o) * 2048 + t] = fmaxf((conv - m) * sc + be, 0.f);
    }
    float cr = rbb[o];
    const float* xp = xb + (size_t)(2 * t) * 8;
#pragma unroll
    for (int c = 0; c < 8; c++) cr += rw[o * 8 + c] * xp[c];
    {
        float g = bnr[o], be = bnr[768 + o], m = bnr[1536 + o], v = bnr[2304 + o];
        float sc = g * rsqrtf(v + EPSF);
        res1[((size_t)b * 768 + o) * 2048 + t] = (cr - m) * sc + be;
    }
}

// ===================== transpose [B,768,512] -> [B,512,768] =====================
__global__ __launch_bounds__(1024) void transpose_k(const float* __restrict__ in,
                                                    float* __restrict__ out)
{
    __shared__ float t[32][33];
    int b = blockIdx.z;
    int l0 = blockIdx.x * 32, d0 = blockIdx.y * 32;
    int tx = threadIdx.x, ty = threadIdx.y;
    t[ty][tx] = in[((size_t)b * 768 + d0 + ty) * 512 + l0 + tx];
    __syncthreads();
    out[((size_t)b * 512 + l0 + ty) * 768 + d0 + tx] = t[tx][ty];
}

// ===================== repack wq/wk/wv [H,D,DQ] -> [D, H*DQ] =====================
__global__ void repack_k(const float* __restrict__ wq, const float* __restrict__ wk,
                         const float* __restrict__ wv,
                         float* __restrict__ Wq, float* __restrict__ Wk, float* __restrict__ Wv)
{
    int i = blockIdx.x * 256 + threadIdx.x;
    if (i >= 768 * 768) return;
    int d = i / 768, rest = i - d * 768;
    int h = rest / 96, qq = rest - h * 96;
    size_t src = ((size_t)h * 768 + d) * 96 + qq;
    Wq[i] = wq[src];
    Wk[i] = wk[src];
    Wv[i] = wv[src];
}

// ===================== QK^T/sqrt(96) + banded rel-pos + mask =====================
// q,k: [B*L, 768] (head h at column h*96); relb: [H][B*L][199]; lg: [B*H,512,512]
__global__ __launch_bounds__(256) void qk_rel_k(
    const float* __restrict__ q, const float* __restrict__ kk,
    const float* __restrict__ relb, float* __restrict__ lg)
{
    int z = blockIdx.z, b = z >> 3, h = z & 7;
    const float* Aq = q  + (size_t)b * 512 * 768 + h * 96;
    const float* Bk = kk + (size_t)b * 512 * 768 + h * 96;
    __shared__ float As[16][68];
    __shared__ float Bs[16][68];
    int tid = threadIdx.x, tx = tid & 15, ty = tid >> 4;
    int i0 = blockIdx.y * 64, j0 = blockIdx.x * 64;
    float acc[4][4] = {};
    for (int kt = 0; kt < 96; kt += 16) {
#pragma unroll
        for (int e = 0; e < 4; e++) {
            int flat = tid + e * 256;
            int k = flat & 15, m = flat >> 4;
            As[k][m] = Aq[(size_t)(i0 + m) * 768 + kt + k];
            Bs[k][m] = Bk[(size_t)(j0 + m) * 768 + kt + k];
        }
        __syncthreads();
#pragma unroll
        for (int k = 0; k < 16; k++) {
            float a[4], b2[4];
#pragma unroll
            for (int i = 0; i < 4; i++) a[i] = As[k][ty * 4 + i];
#pragma unroll
            for (int j = 0; j < 4; j++) b2[j] = Bs[k][tx * 4 + j];
#pragma unroll
            for (int i = 0; i < 4; i++)
#pragma unroll
                for (int j = 0; j < 4; j++)
                    acc[i][j] = fmaf(a[i], b2[j], acc[i][j]);
        }
        __syncthreads();
    }
    const float scale = 0.1020620726159658f;  // 1/sqrt(96)
#pragma unroll
    for (int i = 0; i < 4; i++) {
        int ii = i0 + ty * 4 + i;
        const float* rrow = relb + ((size_t)h * 4096 + (size_t)b * 512 + ii) * 199;
#pragma unroll
        for (int j = 0; j < 4; j++) {
            int jj = j0 + tx * 4 + j;
            float v = acc[i][j] * scale;
            int idx = jj - ii + 99;
            if (idx >= 0 && idx < 199) v += rrow[idx];
            else v += -1e8f;
            lg[(size_t)z * 262144 + (size_t)ii * 512 + jj] = v;
        }
    }
}

// ===================== row softmax (rows of 512) =====================
__global__ __launch_bounds__(256) void softmax_k(float* __restrict__ lg)
{
    __shared__ float red1[4];
    __shared__ float red2[4];
    size_t r = blockIdx.x;
    float* p = lg + r * 512;
    int tid = threadIdx.x;
    float v0 = p[tid], v1 = p[tid + 256];
    float m = fmaxf(v0, v1);
#pragma unroll
    for (int off = 32; off; off >>= 1) m = fmaxf(m, __shfl_xor(m, off));
    if ((tid & 63) == 0) red1[tid >> 6] = m;
    __syncthreads();
    m = fmaxf(fmaxf(red1[0], red1[1]), fmaxf(red1[2], red1[3]));
    float e0 = expf(v0 - m), e1 = expf(v1 - m);
    float s = e0 + e1;
#pragma unroll
    for (int off = 32; off; off >>= 1) s += __shfl_xor(s, off);
    if ((tid & 63) == 0) red2[tid >> 6] = s;
    __syncthreads();
    float inv = 1.f / (red2[0] + red2[1] + red2[2] + red2[3]);
    p[tid] = e0 * inv;
    p[tid + 256] = e1 * inv;
}

// ===================== LayerNorm over 768, rows=4096 =====================
__global__ __launch_bounds__(256) void ln_k(const float* __restrict__ in,
                                            const float* __restrict__ g,
                                            const float* __restrict__ b,
                                            float* __restrict__ out)
{
    __shared__ float red1[4];
    __shared__ float red2[4];
    int r = blockIdx.x, tid = threadIdx.x;
    const float* p = in + (size_t)r * 768;
    float x0 = p[tid], x1 = p[tid + 256], x2 = p[tid + 512];
    float s = x0 + x1 + x2;
#pragma unroll
    for (int off = 32; off; off >>= 1) s += __shfl_xor(s, off);
    if ((tid & 63) == 0) red1[tid >> 6] = s;
    __syncthreads();
    float mu = (red1[0] + red1[1] + red1[2] + red1[3]) * (1.f / 768.f);
    float d0 = x0 - mu, d1 = x1 - mu, d2 = x2 - mu;
    float sq = d0 * d0 + d1 * d1 + d2 * d2;
#pragma unroll
    for (int off = 32; off; off >>= 1) sq += __shfl_xor(sq, off);
    if ((tid & 63) == 0) red2[tid >> 6] = sq;
    __syncthreads();
    float rstd = rsqrtf((red2[0] + red2[1] + red2[2] + red2[3]) * (1.f / 768.f) + EPSF);
    float* q = out + (size_t)r * 768;
    q[tid]       = g[tid]       * d0 * rstd + b[tid];
    q[tid + 256] = g[tid + 256] * d1 * rstd + b[tid + 256];
    q[tid + 512] = g[tid + 512] * d2 * rstd + b[tid + 512];
}

// ===================== host launch =====================
extern "C" void kernel_launch(void* const* d_in, const int* in_sizes, int n_in,
                              void* d_out, int out_size, void* d_ws, size_t ws_size,
                              hipStream_t stream)
{
    const float* x_raw    = (const float*)d_in[0];
    const float* rb1_c1w  = (const float*)d_in[1];
    const float* rb1_c1b  = (const float*)d_in[2];
    const float* rb1_bn1  = (const float*)d_in[3];
    const float* rb1_c2w  = (const float*)d_in[4];
    const float* rb1_c2b  = (const float*)d_in[5];
    const float* rb1_bn2  = (const float*)d_in[6];
    const float* rb1_rw   = (const float*)d_in[7];
    const float* rb1_rb   = (const float*)d_in[8];
    const float* rb1_bnr  = (const float*)d_in[9];
    const float* rb23_c1w = (const float*)d_in[10];
    const float* rb23_c1b = (const float*)d_in[11];
    const float* rb23_bn1 = (const float*)d_in[12];
    const float* rb23_c2w = (const float*)d_in[13];
    const float* rb23_c2b = (const float*)d_in[14];
    const float* rb23_bn2 = (const float*)d_in[15];
    const float* rb23_rw  = (const float*)d_in[16];
    const float* rb23_rb  = (const float*)d_in[17];
    const float* rb23_bnr = (const float*)d_in[18];
    const float* w_in_w   = (const float*)d_in[19];
    const float* w_in_b   = (const float*)d_in[20];
    const float* wq       = (const float*)d_in[21];
    const float* wk       = (const float*)d_in[22];
    const float* wv       = (const float*)d_in[23];
    const float* wo       = (const float*)d_in[24];
    const float* rel_emb  = (const float*)d_in[25];
    const float* ln1_g    = (const float*)d_in[26];
    const float* ln1_b    = (const float*)d_in[27];
    const float* ln2_g    = (const float*)d_in[28];
    const float* ln2_b    = (const float*)d_in[29];
    const float* ff1_w    = (const float*)d_in[30];
    const float* ff1_b    = (const float*)d_in[31];
    const float* ff2_w    = (const float*)d_in[32];
    const float* ff2_b    = (const float*)d_in[33];
    const float* w_out_w  = (const float*)d_in[34];
    const float* w_out_b  = (const float*)d_in[35];
    float* out = (float*)d_out;

    float* ws = (float*)d_ws;
    float* P0 = ws;                 // 12582912 floats
    float* P1 = ws + 12582912;      // 12582912
    float* P2 = ws + 25165824;      // 12582912
    float* P3 = ws + 37748736;      // 16777216 (logits)   total ~218 MB

    // ---- conv stack: T 4096 -> 2048 -> 1024 -> 512 ----
    rb1_front_k<<<dim3(32, 192, 8), 256, 0, stream>>>(x_raw, rb1_c1w, rb1_c1b, rb1_bn1,
                                                      rb1_rw, rb1_rb, rb1_bnr, P0, P1);
    convgemm_k<<<dim3(32, 12, 8), 256, 0, stream>>>(P0, rb1_c2w, rb1_c2b, rb1_bn2, P1, P2,
                                                    2048, 2048, 3, 1, 1, 1);
    // rb2
    convgemm_k<<<dim3(16, 12, 8), 256, 0, stream>>>(P2, rb23_c1w, rb23_c1b, rb23_bn1, nullptr, P0,
                                                    2048, 1024, 3, 2, 1, 1);
    convgemm_k<<<dim3(16, 12, 8), 256, 0, stream>>>(P2, rb23_rw, rb23_rb, rb23_bnr, nullptr, P1,
                                                    2048, 1024, 1, 2, 0, 0);
    convgemm_k<<<dim3(16, 12, 8), 256, 0, stream>>>(P0, rb23_c2w, rb23_c2b, rb23_bn2, P1, P2,
                                                    1024, 1024, 3, 1, 1, 1);
    // rb3 (second entry of rb23 arrays)
    convgemm_k<<<dim3(8, 12, 8), 256, 0, stream>>>(P2, rb23_c1w + 1769472, rb23_c1b + 768,
                                                   rb23_bn1 + 3072, nullptr, P0, 1024, 512, 3, 2, 1, 1);
    convgemm_k<<<dim3(8, 12, 8), 256, 0, stream>>>(P2, rb23_rw + 589824, rb23_rb + 768,
                                                   rb23_bnr + 3072, nullptr, P1, 1024, 512, 1, 2, 0, 0);
    convgemm_k<<<dim3(8, 12, 8), 256, 0, stream>>>(P0, rb23_c2w + 1769472, rb23_c2b + 768,
                                                   rb23_bn2 + 3072, P1, P2, 512, 512, 3, 1, 1, 1);

    // ---- transpose to [B, L=512, D=768] ----
    float* xt = P2 + 3145728;
    transpose_k<<<dim3(16, 24, 8), dim3(32, 32), 0, stream>>>(P2, xt);

    float* xb   = P0;               // residual stream [4096,768]
    float* qb   = P0 + 3145728;
    float* kb   = P0 + 6291456;
    float* vb   = P0 + 9437184;
    float* relb = P1;               // [H][4096][199]
    float* ffh  = P1;               // [4096,3072] (disjoint in time from relb)
    float* atno = P2;               // [4096,768]
    float* tmp  = P2 + 3145728;
    float* Wq   = P2 + 6291456;
    float* Wk   = Wq + 589824;
    float* Wv   = Wk + 589824;
    float* lg   = P3;               // [64,512,512]

    // w_in
    gemm_k<true, false, true, false><<<dim3(12, 64, 1), 256, 0, stream>>>(
        xt, w_in_w, w_in_b, nullptr, xb, 4096, 768, 768, 768, 768, 768, 1, 0, 0, 0, 0, 0, 0);

    for (int l = 0; l < 6; l++) {
        repack_k<<<dim3(2304), 256, 0, stream>>>(wq + (size_t)l * 589824, wk + (size_t)l * 589824,
                                                 wv + (size_t)l * 589824, Wq, Wk, Wv);
        gemm_k<false, false, false, false><<<dim3(12, 64, 1), 256, 0, stream>>>(
            xb, Wq, nullptr, nullptr, qb, 4096, 768, 768, 768, 768, 768, 1, 0, 0, 0, 0, 0, 0);
        gemm_k<false, false, false, false><<<dim3(12, 64, 1), 256, 0, stream>>>(
            xb, Wk, nullptr, nullptr, kb, 4096, 768, 768, 768, 768, 768, 1, 0, 0, 0, 0, 0, 0);
        gemm_k<false, false, false, false><<<dim3(12, 64, 1), 256, 0, stream>>>(
            xb, Wv, nullptr, nullptr, vb, 4096, 768, 768, 768, 768, 768, 1, 0, 0, 0, 0, 0, 0);
        // rel_logits: per-head GEMM q[:, h*96:+96] x rel[h]^T -> relb[h]
        gemm_k<true, false, false, false><<<dim3(4, 64, 8), 256, 0, stream>>>(
            qb, rel_emb + (size_t)l * 152832, nullptr, nullptr, relb,
            4096, 199, 96, 768, 96, 199, 8, 0, 96, 0, 19104, 0, 815104);
        qk_rel_k<<<dim3(8, 8, 64), 256, 0, stream>>>(qb, kb, relb, lg);
        softmax_k<<<dim3(32768), 256, 0, stream>>>(lg);
        // PV: per (b,h) [512,512]x[512,96]
        gemm_k<false, false, false, false><<<dim3(2, 8, 64), 256, 0, stream>>>(
            lg, vb, nullptr, nullptr, atno,
            512, 96, 512, 512, 768, 768, 8, 2097152, 262144, 393216, 96, 393216, 96);
        // out-proj + residual
        gemm_k<false, false, false, true><<<dim3(12, 64, 1), 256, 0, stream>>>(
            atno, wo + (size_t)l * 589824, nullptr, xb, tmp,
            4096, 768, 768, 768, 768, 768, 1, 0, 0, 0, 0, 0, 0);
        ln_k<<<dim3(4096), 256, 0, stream>>>(tmp, ln1_g + l * 768, ln1_b + l * 768, xb);
        // FF
        gemm_k<true, true, true, false><<<dim3(48, 64, 1), 256, 0, stream>>>(
            xb, ff1_w + (size_t)l * 2359296, ff1_b + l * 3072, nullptr, ffh,
            4096, 3072, 768, 768, 768, 3072, 1, 0, 0, 0, 0, 0, 0);
        gemm_k<true, false, true, true><<<dim3(12, 64, 1), 256, 0, stream>>>(
            ffh, ff2_w + (size_t)l * 2359296, ff2_b + l * 768, xb, tmp,
            4096, 768, 3072, 3072, 3072, 768, 1, 0, 0, 0, 0, 0, 0);
        ln_k<<<dim3(4096), 256, 0, stream>>>(tmp, ln2_g + l * 768, ln2_b + l * 768, xb);
    }

    // output head
    gemm_k<true, false, true, false><<<dim3(16, 64, 1), 256, 0, stream>>>(
        xb, w_out_w, w_out_b, nullptr, out, 4096, 1024, 768, 768, 768, 1024, 1, 0, 0, 0, 0, 0, 0);
}

// Round 2
// 3078.717 us; speedup vs baseline: 3.5976x; 3.5976x over previous
//
#include <hip/hip_runtime.h>
#include <math.h>

typedef __bf16 bf16;
typedef bf16 bf16x8 __attribute__((ext_vector_type(8)));
typedef bf16 bf16x4 __attribute__((ext_vector_type(4)));
typedef float f32x4 __attribute__((ext_vector_type(4)));
#define EPSF 1e-5f

__device__ __forceinline__ void ldg_lds16(const bf16* g, bf16* l) {
    __builtin_amdgcn_global_load_lds((const __attribute__((address_space(1))) void*)g,
                                     (__attribute__((address_space(3))) void*)l, 16, 0, 0);
}

// ===================== generic bf16 MFMA GEMM: C = A[M,K] x B[N,K]^T =====================
// 128x128 tile, BK=32, 256 thr = 4 waves (2x2), each wave 64x64 via 4x4 frags of 16x16x32.
template<bool BIAS, bool RESF, bool RELU, bool WF, bool WB>
__global__ __launch_bounds__(256) void mgemm_k(
    const bf16* __restrict__ A, const bf16* __restrict__ B,
    const float* __restrict__ bias, const float* __restrict__ resf,
    float* __restrict__ Cf, bf16* __restrict__ Cb,
    int K, int lda, int ldb, int ldc, int Nstore,
    int Z2, long long sA1, long long sA2, long long sB1, long long sB2,
    long long sC1, long long sC2)
{
    int z = blockIdx.z;
    int z1 = z / Z2, z2 = z - z1 * Z2;
    A += z1 * sA1 + z2 * sA2;
    B += z1 * sB1 + z2 * sB2;
    long long coff = z1 * sC1 + z2 * sC2;

    __shared__ __align__(16) bf16 As[4096];
    __shared__ __align__(16) bf16 Bs[4096];
    int tid = threadIdx.x, wid = tid >> 6, lane = tid & 63;
    int m0 = blockIdx.y * 128, n0 = blockIdx.x * 128;
    int wr = wid >> 1, wc = wid & 1;
    int lrow = lane & 15, lk8 = (lane >> 4) * 8;
    int srow = wid * 32 + (lane >> 2);
    int scol = (lane & 3) * 8;
    f32x4 acc[4][4] = {};

    for (int kt = 0; kt < K; kt += 32) {
        ldg_lds16(A + (size_t)(m0 + srow) * lda + kt + scol, As + wid * 1024);
        ldg_lds16(A + (size_t)(m0 + srow + 16) * lda + kt + scol, As + wid * 1024 + 512);
        ldg_lds16(B + (size_t)(n0 + srow) * ldb + kt + scol, Bs + wid * 1024);
        ldg_lds16(B + (size_t)(n0 + srow + 16) * ldb + kt + scol, Bs + wid * 1024 + 512);
        __syncthreads();
        bf16x8 af[4], bfr[4];
#pragma unroll
        for (int i = 0; i < 4; i++) {
            af[i]  = *(const bf16x8*)(As + (wr * 64 + i * 16 + lrow) * 32 + lk8);
            bfr[i] = *(const bf16x8*)(Bs + (wc * 64 + i * 16 + lrow) * 32 + lk8);
        }
#pragma unroll
        for (int i = 0; i < 4; i++)
#pragma unroll
            for (int j = 0; j < 4; j++)
                acc[i][j] = __builtin_amdgcn_mfma_f32_16x16x32_bf16(af[i], bfr[j], acc[i][j], 0, 0, 0);
        __syncthreads();
    }
    int mtop = m0 + wr * 64 + (lane >> 4) * 4;
    int ntop = n0 + wc * 64 + lrow;
#pragma unroll
    for (int mi = 0; mi < 4; mi++) {
#pragma unroll
        for (int r = 0; r < 4; r++) {
            int m = mtop + mi * 16 + r;
            long long ro = coff + (long long)m * ldc;
#pragma unroll
            for (int ni = 0; ni < 4; ni++) {
                int n = ntop + ni * 16;
                float v = acc[mi][ni][r];
                if (BIAS) v += bias[n];
                if (RESF) v += resf[ro + n];
                if (RELU) v = fmaxf(v, 0.f);
                if (n < Nstore) {
                    if (WF) Cf[ro + n] = v;
                    if (WB) Cb[ro + n] = (bf16)v;
                }
            }
        }
    }
}

// ===================== conv1d as MFMA GEMM: C[t,o], t-major padded activations =====================
// in: [z][Tin+2][768] bf16 (halo rows zero); w: [768][KK] bf16 (k = kq*768+ic); out row t at outoff+t.
template<bool RES, bool RELU>
__global__ __launch_bounds__(256) void conv_k(
    const bf16* __restrict__ in, const bf16* __restrict__ w,
    const float* __restrict__ scsh, const bf16* __restrict__ res, bf16* __restrict__ out,
    int KK, int stride, int rowoff, long long instrideB, long long outstrideB, int outoff,
    long long resstrideB)
{
    int z = blockIdx.z;
    int n0 = blockIdx.x * 128, m0 = blockIdx.y * 128;
    __shared__ __align__(16) bf16 As[4096];
    __shared__ __align__(16) bf16 Bs[4096];
    int tid = threadIdx.x, wid = tid >> 6, lane = tid & 63;
    int wr = wid >> 1, wc = wid & 1;
    int lrow = lane & 15, lk8 = (lane >> 4) * 8;
    int srow = wid * 32 + (lane >> 2);
    int scol = (lane & 3) * 8;
    const bf16* inz = in + (size_t)z * instrideB;
    f32x4 acc[4][4] = {};

    for (int kt = 0; kt < KK; kt += 32) {
        int kq = kt / 768;
        int ic0 = kt - kq * 768;
        ldg_lds16(inz + (size_t)((m0 + srow) * stride + kq + rowoff) * 768 + ic0 + scol, As + wid * 1024);
        ldg_lds16(inz + (size_t)((m0 + srow + 16) * stride + kq + rowoff) * 768 + ic0 + scol, As + wid * 1024 + 512);
        ldg_lds16(w + (size_t)(n0 + srow) * KK + kt + scol, Bs + wid * 1024);
        ldg_lds16(w + (size_t)(n0 + srow + 16) * KK + kt + scol, Bs + wid * 1024 + 512);
        __syncthreads();
        bf16x8 af[4], bfr[4];
#pragma unroll
        for (int i = 0; i < 4; i++) {
            af[i]  = *(const bf16x8*)(As + (wr * 64 + i * 16 + lrow) * 32 + lk8);
            bfr[i] = *(const bf16x8*)(Bs + (wc * 64 + i * 16 + lrow) * 32 + lk8);
        }
#pragma unroll
        for (int i = 0; i < 4; i++)
#pragma unroll
            for (int j = 0; j < 4; j++)
                acc[i][j] = __builtin_amdgcn_mfma_f32_16x16x32_bf16(af[i], bfr[j], acc[i][j], 0, 0, 0);
        __syncthreads();
    }
    bf16* outz = out + (size_t)z * outstrideB + (size_t)outoff * 768;
    const bf16* resz = res + (RES ? (size_t)z * resstrideB : 0);
    int mtop = m0 + wr * 64 + (lane >> 4) * 4;
    int ntop = n0 + wc * 64 + lrow;
#pragma unroll
    for (int mi = 0; mi < 4; mi++) {
#pragma unroll
        for (int r = 0; r < 4; r++) {
            int m = mtop + mi * 16 + r;
#pragma unroll
            for (int ni = 0; ni < 4; ni++) {
                int n = ntop + ni * 16;
                float v = acc[mi][ni][r] * scsh[n] + scsh[768 + n];
                if (RES) v += (float)resz[(size_t)m * 768 + n];
                if (RELU) v = fmaxf(v, 0.f);
                outz[(size_t)m * 768 + n] = (bf16)v;
            }
        }
    }
}

// ===================== QK^T*scale + banded rel-pos + mask, with band early-out =====================
__global__ __launch_bounds__(256) void qkrel_k(
    const bf16* __restrict__ qkv, const float* __restrict__ relb, float* __restrict__ lg)
{
    int z = blockIdx.z, b = z >> 3, h = z & 7;
    int i0 = blockIdx.y * 128, j0 = blockIdx.x * 128;
    long long lgbase = (long long)z * 262144;
    int tid = threadIdx.x;
    if (i0 - j0 > 226 || j0 - i0 > 226) {
        float4 f = make_float4(-1e8f, -1e8f, -1e8f, -1e8f);
        int rr0 = tid >> 4, cc = (tid & 15) * 8;
#pragma unroll
        for (int s = 0; s < 8; s++) {
            float* p = lg + lgbase + (long long)(i0 + s * 16 + rr0) * 512 + j0 + cc;
            ((float4*)p)[0] = f; ((float4*)p)[1] = f;
        }
        return;
    }
    const bf16* Aq = qkv + (size_t)b * 512 * 2304 + h * 96;
    const bf16* Bk = Aq + 768;
    __shared__ __align__(16) bf16 As[4096];
    __shared__ __align__(16) bf16 Bs[4096];
    int wid = tid >> 6, lane = tid & 63;
    int wr = wid >> 1, wc = wid & 1;
    int lrow = lane & 15, lk8 = (lane >> 4) * 8;
    int srow = wid * 32 + (lane >> 2);
    int scol = (lane & 3) * 8;
    f32x4 acc[4][4] = {};
    for (int kt = 0; kt < 96; kt += 32) {
        ldg_lds16(Aq + (size_t)(i0 + srow) * 2304 + kt + scol, As + wid * 1024);
        ldg_lds16(Aq + (size_t)(i0 + srow + 16) * 2304 + kt + scol, As + wid * 1024 + 512);
        ldg_lds16(Bk + (size_t)(j0 + srow) * 2304 + kt + scol, Bs + wid * 1024);
        ldg_lds16(Bk + (size_t)(j0 + srow + 16) * 2304 + kt + scol, Bs + wid * 1024 + 512);
        __syncthreads();
        bf16x8 af[4], bfr[4];
#pragma unroll
        for (int i = 0; i < 4; i++) {
            af[i]  = *(const bf16x8*)(As + (wr * 64 + i * 16 + lrow) * 32 + lk8);
            bfr[i] = *(const bf16x8*)(Bs + (wc * 64 + i * 16 + lrow) * 32 + lk8);
        }
#pragma unroll
        for (int i = 0; i < 4; i++)
#pragma unroll
            for (int j = 0; j < 4; j++)
                acc[i][j] = __builtin_amdgcn_mfma_f32_16x16x32_bf16(af[i], bfr[j], acc[i][j], 0, 0, 0);
        __syncthreads();
    }
    const float sc = 0.10206207261596577f;  // 1/sqrt(96)
    int itop = i0 + wr * 64 + (lane >> 4) * 4;
    int jtop = j0 + wc * 64 + lrow;
#pragma unroll
    for (int mi = 0; mi < 4; mi++) {
#pragma unroll
        for (int r = 0; r < 4; r++) {
            int i = itop + mi * 16 + r;
            const float* rrow = relb + ((long long)h * 4096 + b * 512 + i) * 256;
#pragma unroll
            for (int ni = 0; ni < 4; ni++) {
                int j = jtop + ni * 16;
                float v = acc[mi][ni][r] * sc;
                int idx = j - i + 99;
                v += (idx >= 0 && idx < 199) ? rrow[idx] : -1e8f;
                lg[lgbase + (long long)i * 512 + j] = v;
            }
        }
    }
}

// ===================== row softmax fp32 -> bf16 in place =====================
__global__ __launch_bounds__(256) void softmax_k(float* __restrict__ lg)
{
    __shared__ float red1[4];
    __shared__ float red2[4];
    size_t r = blockIdx.x;
    float* p = lg + r * 512;
    int tid = threadIdx.x;
    float v0 = p[tid], v1 = p[tid + 256];
    float m = fmaxf(v0, v1);
#pragma unroll
    for (int off = 32; off; off >>= 1) m = fmaxf(m, __shfl_xor(m, off));
    if ((tid & 63) == 0) red1[tid >> 6] = m;
    __syncthreads();
    m = fmaxf(fmaxf(red1[0], red1[1]), fmaxf(red1[2], red1[3]));
    float e0 = expf(v0 - m), e1 = expf(v1 - m);
    float s = e0 + e1;
#pragma unroll
    for (int off = 32; off; off >>= 1) s += __shfl_xor(s, off);
    if ((tid & 63) == 0) red2[tid >> 6] = s;
    __syncthreads();
    float inv = 1.f / (red2[0] + red2[1] + red2[2] + red2[3]);
    bf16* pb = (bf16*)p;
    pb[tid] = (bf16)(e0 * inv);
    pb[tid + 256] = (bf16)(e1 * inv);
}

// ===================== LayerNorm fp32 in, fp32 + bf16 out =====================
__global__ __launch_bounds__(256) void ln2_k(const float* __restrict__ in,
                                             const float* __restrict__ g,
                                             const float* __restrict__ b,
                                             float* __restrict__ xf, bf16* __restrict__ xb)
{
    __shared__ float red1[4];
    __shared__ float red2[4];
    int r = blockIdx.x, tid = threadIdx.x;
    const float* p = in + (size_t)r * 768;
    float x0 = p[tid], x1 = p[tid + 256], x2 = p[tid + 512];
    float s = x0 + x1 + x2;
#pragma unroll
    for (int off = 32; off; off >>= 1) s += __shfl_xor(s, off);
    if ((tid & 63) == 0) red1[tid >> 6] = s;
    __syncthreads();
    float mu = (red1[0] + red1[1] + red1[2] + red1[3]) * (1.f / 768.f);
    float d0 = x0 - mu, d1 = x1 - mu, d2 = x2 - mu;
    float sq = d0 * d0 + d1 * d1 + d2 * d2;
#pragma unroll
    for (int off = 32; off; off >>= 1) sq += __shfl_xor(sq, off);
    if ((tid & 63) == 0) red2[tid >> 6] = sq;
    __syncthreads();
    float rstd = rsqrtf((red2[0] + red2[1] + red2[2] + red2[3]) * (1.f / 768.f) + EPSF);
    float o0 = g[tid] * d0 * rstd + b[tid];
    float o1 = g[tid + 256] * d1 * rstd + b[tid + 256];
    float o2 = g[tid + 512] * d2 * rstd + b[tid + 512];
    size_t base = (size_t)r * 768;
    xf[base + tid] = o0;       xb[base + tid] = (bf16)o0;
    xf[base + tid + 256] = o1; xb[base + tid + 256] = (bf16)o1;
    xf[base + tid + 512] = o2; xb[base + tid + 512] = (bf16)o2;
}

// ===================== resblock1 front (CIN=8) -> bf16 t-major =====================
__global__ __launch_bounds__(256) void rb1_front_k(
    const float* __restrict__ xr, const float* __restrict__ c1w, const float* __restrict__ rw,
    const float* __restrict__ scsh0, const float* __restrict__ scsh1,
    bf16* __restrict__ h1, bf16* __restrict__ res1)
{
    int t = blockIdx.x, b = blockIdx.y, tid = threadIdx.x;
    const float* xb = xr + (size_t)b * 4096 * 8;
    float xv[3][8];
#pragma unroll
    for (int k = 0; k < 3; k++) {
        int pos = 2 * t + k - 1;
        bool ok = (unsigned)pos < 4096u;
        const float* xp = xb + (size_t)pos * 8;
#pragma unroll
        for (int c = 0; c < 8; c++) xv[k][c] = ok ? xp[c] : 0.f;
    }
#pragma unroll
    for (int rep = 0; rep < 3; rep++) {
        int o = rep * 256 + tid;
        float conv = 0.f;
        const float* wp = c1w + (size_t)o * 24;
#pragma unroll
        for (int c = 0; c < 8; c++)
#pragma unroll
            for (int k = 0; k < 3; k++) conv = fmaf(wp[c * 3 + k], xv[k][c], conv);
        float hv = fmaxf(conv * scsh0[o] + scsh0[768 + o], 0.f);
        h1[((size_t)b * 2050 + t + 1) * 768 + o] = (bf16)hv;
        float cr = 0.f;
        const float* rp = rw + (size_t)o * 8;
#pragma unroll
        for (int c = 0; c < 8; c++) cr = fmaf(rp[c], xv[1][c], cr);
        res1[((size_t)b * 2048 + t) * 768 + o] = (bf16)(cr * scsh1[o] + scsh1[768 + o]);
    }
}

// ===================== small prep kernels =====================
__global__ void bnprep_k(const float* __restrict__ bn, const float* __restrict__ cb,
                         float* __restrict__ scsh)
{
    int i = blockIdx.x * 256 + threadIdx.x;
    if (i >= 768) return;
    float g = bn[i], be = bn[768 + i], m = bn[1536 + i], v = bn[2304 + i];
    float sc = g * rsqrtf(v + EPSF);
    scsh[i] = sc;
    scsh[768 + i] = (cb[i] - m) * sc + be;
}

__global__ void zeropad_k(bf16* __restrict__ buf, int T)
{
    int i = blockIdx.x * 256 + threadIdx.x;
    if (i >= 768) return;
    int row = blockIdx.y ? (T + 1) : 0;
    buf[((size_t)blockIdx.z * (T + 2) + row) * 768 + i] = (bf16)0.f;
}

__global__ void rep3_k(const float* __restrict__ w, bf16* __restrict__ wr)
{
    long long i = (long long)blockIdx.x * 256 + threadIdx.x;
    if (i >= 1769472) return;
    int o = i / 2304, k = i - (long long)o * 2304;
    int kq = k / 768, ic = k - kq * 768;
    wr[i] = (bf16)w[((long long)o * 768 + ic) * 3 + kq];
}

__global__ void cast4_k(const float* __restrict__ s, bf16* __restrict__ d, int n4)
{
    int i = blockIdx.x * 256 + threadIdx.x;
    if (i >= n4) return;
    float4 v = ((const float4*)s)[i];
    bf16x4 o = {(bf16)v.x, (bf16)v.y, (bf16)v.z, (bf16)v.w};
    ((bf16x4*)d)[i] = o;
}

// per-layer weight prep: Wqkv[2304][768], Wo[768][768], Rel[8][256][96] pad, F1/F2 casts
__global__ void layerprep_k(const float* __restrict__ wq, const float* __restrict__ wk,
                            const float* __restrict__ wv, const float* __restrict__ wo,
                            const float* __restrict__ rel,
                            const float* __restrict__ ff1, const float* __restrict__ ff2,
                            bf16* __restrict__ Wqkv, bf16* __restrict__ Wo,
                            bf16* __restrict__ Rel, bf16* __restrict__ F1, bf16* __restrict__ F2)
{
    long long i = (long long)blockIdx.x * 256 + threadIdx.x;
    const long long S0 = 1769472, S1 = 589824, S2 = 196608, S3 = 2359296;
    if (i < S0) {
        int n = i / 768, k = i - (long long)n * 768;
        int sel = n / 768, hq = n - sel * 768;
        int h = hq / 96, q = hq - h * 96;
        const float* src = sel == 0 ? wq : (sel == 1 ? wk : wv);
        Wqkv[i] = (bf16)src[((long long)h * 768 + k) * 96 + q];
    } else if (i < S0 + S1) {
        long long j = i - S0;
        int n = j / 768, kk = j - (long long)n * 768;
        Wo[j] = (bf16)wo[(long long)kk * 768 + n];
    } else if (i < S0 + S1 + S2) {
        long long j = i - S0 - S1;
        int h = j / 24576, rest = j - (long long)h * 24576;
        int rr = rest / 96, q = rest - rr * 96;
        Rel[j] = rr < 199 ? (bf16)rel[((long long)h * 199 + rr) * 96 + q] : (bf16)0.f;
    } else if (i < S0 + S1 + S2 + S3) {
        long long j = i - S0 - S1 - S2;
        F1[j] = (bf16)ff1[j];
    } else {
        long long j = i - S0 - S1 - S2 - S3;
        F2[j] = (bf16)ff2[j];
    }
}

// vt[z=(b*8+h)][q 0..127][t 0..511] = v part of qkv, rows 96..127 zero
__global__ __launch_bounds__(256) void vt_k(const bf16* __restrict__ qkv, bf16* __restrict__ vt)
{
    int z = blockIdx.z, b = z >> 3, h = z & 7;
    int t0 = blockIdx.x * 32, q0 = blockIdx.y * 32;
    __shared__ bf16 sm[32][33];
    int tx = threadIdx.x & 31, ty = threadIdx.x >> 5;
#pragma unroll
    for (int s = 0; s < 4; s++) {
        int t = t0 + ty + s * 8, q = q0 + tx;
        sm[ty + s * 8][tx] = (q < 96) ? qkv[((size_t)b * 512 + t) * 2304 + 1536 + h * 96 + q]
                                      : (bf16)0.f;
    }
    __syncthreads();
#pragma unroll
    for (int s = 0; s < 4; s++) {
        int q = q0 + ty + s * 8;
        vt[((size_t)z * 128 + q) * 512 + t0 + tx] = sm[tx][ty + s * 8];
    }
}

// ===================== host launch =====================
extern "C" void kernel_launch(void* const* d_in, const int* in_sizes, int n_in,
                              void* d_out, int out_size, void* d_ws, size_t ws_size,
                              hipStream_t stream)
{
    const float* x_raw    = (const float*)d_in[0];
    const float* rb1_c1w  = (const float*)d_in[1];
    const float* rb1_c1b  = (const float*)d_in[2];
    const float* rb1_bn1  = (const float*)d_in[3];
    const float* rb1_c2w  = (const float*)d_in[4];
    const float* rb1_c2b  = (const float*)d_in[5];
    const float* rb1_bn2  = (const float*)d_in[6];
    const float* rb1_rw   = (const float*)d_in[7];
    const float* rb1_rb   = (const float*)d_in[8];
    const float* rb1_bnr  = (const float*)d_in[9];
    const float* rb23_c1w = (const float*)d_in[10];
    const float* rb23_c1b = (const float*)d_in[11];
    const float* rb23_bn1 = (const float*)d_in[12];
    const float* rb23_c2w = (const float*)d_in[13];
    const float* rb23_c2b = (const float*)d_in[14];
    const float* rb23_bn2 = (const float*)d_in[15];
    const float* rb23_rw  = (const float*)d_in[16];
    const float* rb23_rb  = (const float*)d_in[17];
    const float* rb23_bnr = (const float*)d_in[18];
    const float* w_in_w   = (const float*)d_in[19];
    const float* w_in_b   = (const float*)d_in[20];
    const float* wq       = (const float*)d_in[21];
    const float* wk       = (const float*)d_in[22];
    const float* wv       = (const float*)d_in[23];
    const float* wo       = (const float*)d_in[24];
    const float* rel_emb  = (const float*)d_in[25];
    const float* ln1_g    = (const float*)d_in[26];
    const float* ln1_b    = (const float*)d_in[27];
    const float* ln2_g    = (const float*)d_in[28];
    const float* ln2_b    = (const float*)d_in[29];
    const float* ff1_w    = (const float*)d_in[30];
    const float* ff1_b    = (const float*)d_in[31];
    const float* ff2_w    = (const float*)d_in[32];
    const float* ff2_b    = (const float*)d_in[33];
    const float* w_out_w  = (const float*)d_in[34];
    const float* w_out_b  = (const float*)d_in[35];
    float* out = (float*)d_out;

    char* W = (char*)d_ws;
    bf16*  h1buf  = (bf16*)(W + 0);           // h1/h2/h3 (padded t-major)
    bf16*  resbuf = (bf16*)(W + 26000000);    // res1/r2/r3
    bf16*  xbuf   = (bf16*)(W + 52000000);    // x1/x2/x3
    float* lg     = (float*)(W + 0);          // 67.1MB logits (transformer phase)
    bf16*  wc3    = (bf16*)(W + 78000000);
    bf16*  wc1    = (bf16*)(W + 82000000);
    float* scsh   = (float*)(W + 84000000);   // 9 slots of [2][768]
    float* xf     = (float*)(W + 85000000);
    bf16*  xb     = (bf16*)(W + 98000000);
    bf16*  qkv    = (bf16*)(W + 105000000);
    bf16*  vt     = (bf16*)(W + 124000000);
    float* relb   = (float*)(W + 133000000);  // shares region with ffh
    bf16*  ffh    = (bf16*)(W + 133000000);
    bf16*  atno   = (bf16*)(W + 167000000);
    float* tmp    = (float*)(W + 174000000);
    bf16*  Wqkv   = (bf16*)(W + 187000000);
    bf16*  Wo     = (bf16*)(W + 191000000);
    bf16*  F1     = (bf16*)(W + 193000000);
    bf16*  F2     = (bf16*)(W + 198000000);
    bf16*  Relp   = (bf16*)(W + 203000000);
    bf16*  Wout   = (bf16*)(W + 204000000);
    bf16*  Winw   = (bf16*)(W + 206000000);

    // ---- BN fold: slots 0 rb1_bn1, 1 rb1_bnr, 2 rb1_bn2, 3 rb2_bn1, 4 rb2_bnr, 5 rb2_bn2,
    //               6 rb3_bn1, 7 rb3_bnr, 8 rb3_bn2
    bnprep_k<<<3, 256, 0, stream>>>(rb1_bn1, rb1_c1b, scsh + 0 * 1536);
    bnprep_k<<<3, 256, 0, stream>>>(rb1_bnr, rb1_rb,  scsh + 1 * 1536);
    bnprep_k<<<3, 256, 0, stream>>>(rb1_bn2, rb1_c2b, scsh + 2 * 1536);
    bnprep_k<<<3, 256, 0, stream>>>(rb23_bn1, rb23_c1b, scsh + 3 * 1536);
    bnprep_k<<<3, 256, 0, stream>>>(rb23_bnr, rb23_rb,  scsh + 4 * 1536);
    bnprep_k<<<3, 256, 0, stream>>>(rb23_bn2, rb23_c2b, scsh + 5 * 1536);
    bnprep_k<<<3, 256, 0, stream>>>(rb23_bn1 + 3072, rb23_c1b + 768, scsh + 6 * 1536);
    bnprep_k<<<3, 256, 0, stream>>>(rb23_bnr + 3072, rb23_rb + 768,  scsh + 7 * 1536);
    bnprep_k<<<3, 256, 0, stream>>>(rb23_bn2 + 3072, rb23_c2b + 768, scsh + 8 * 1536);

    // ---- conv stack, t-major bf16, T 4096->2048->1024->512 ----
    rb1_front_k<<<dim3(2048, 8), 256, 0, stream>>>(x_raw, rb1_c1w, rb1_rw,
                                                   scsh, scsh + 1536, h1buf, resbuf);
    zeropad_k<<<dim3(3, 2, 8), 256, 0, stream>>>(h1buf, 2048);
    // rb1 conv2
    rep3_k<<<6912, 256, 0, stream>>>(rb1_c2w, wc3);
    conv_k<true, true><<<dim3(6, 16, 8), 256, 0, stream>>>(
        h1buf, wc3, scsh + 2 * 1536, resbuf, xbuf, 2304, 1, 0,
        (long long)2050 * 768, (long long)2050 * 768, 1, (long long)2048 * 768);
    zeropad_k<<<dim3(3, 2, 8), 256, 0, stream>>>(xbuf, 2048);
    // rb2
    rep3_k<<<6912, 256, 0, stream>>>(rb23_c1w, wc3);
    conv_k<false, true><<<dim3(6, 8, 8), 256, 0, stream>>>(
        xbuf, wc3, scsh + 3 * 1536, nullptr, h1buf, 2304, 2, 0,
        (long long)2050 * 768, (long long)1026 * 768, 1, 0);
    zeropad_k<<<dim3(3, 2, 8), 256, 0, stream>>>(h1buf, 1024);
    cast4_k<<<576, 256, 0, stream>>>(rb23_rw, wc1, 147456);
    conv_k<false, false><<<dim3(6, 8, 8), 256, 0, stream>>>(
        xbuf, wc1, scsh + 4 * 1536, nullptr, resbuf, 768, 2, 1,
        (long long)2050 * 768, (long long)1024 * 768, 0, 0);
    rep3_k<<<6912, 256, 0, stream>>>(rb23_c2w, wc3);
    conv_k<true, true><<<dim3(6, 8, 8), 256, 0, stream>>>(
        h1buf, wc3, scsh + 5 * 1536, resbuf, xbuf, 2304, 1, 0,
        (long long)1026 * 768, (long long)1026 * 768, 1, (long long)1024 * 768);
    zeropad_k<<<dim3(3, 2, 8), 256, 0, stream>>>(xbuf, 1024);
    // rb3
    rep3_k<<<6912, 256, 0, stream>>>(rb23_c1w + 1769472, wc3);
    conv_k<false, true><<<dim3(6, 4, 8), 256, 0, stream>>>(
        xbuf, wc3, scsh + 6 * 1536, nullptr, h1buf, 2304, 2, 0,
        (long long)1026 * 768, (long long)514 * 768, 1, 0);
    zeropad_k<<<dim3(3, 2, 8), 256, 0, stream>>>(h1buf, 512);
    cast4_k<<<576, 256, 0, stream>>>(rb23_rw + 589824, wc1, 147456);
    conv_k<false, false><<<dim3(6, 4, 8), 256, 0, stream>>>(
        xbuf, wc1, scsh + 7 * 1536, nullptr, resbuf, 768, 2, 1,
        (long long)1026 * 768, (long long)512 * 768, 0, 0);
    rep3_k<<<6912, 256, 0, stream>>>(rb23_c2w + 1769472, wc3);
    conv_k<true, true><<<dim3(6, 4, 8), 256, 0, stream>>>(
        h1buf, wc3, scsh + 8 * 1536, resbuf, xbuf, 2304, 1, 0,
        (long long)514 * 768, (long long)512 * 768, 0, (long long)512 * 768);
    // xbuf now = x3 [4096][768] bf16 (t-major, unpadded) = transformer input

    // ---- transformer ----
    cast4_k<<<576, 256, 0, stream>>>(w_in_w, Winw, 147456);
    cast4_k<<<768, 256, 0, stream>>>(w_out_w, Wout, 196608);
    mgemm_k<true, false, false, true, true><<<dim3(6, 32, 1), 256, 0, stream>>>(
        xbuf, Winw, w_in_b, nullptr, xf, xb, 768, 768, 768, 768, 768, 1, 0, 0, 0, 0, 0, 0);

    for (int l = 0; l < 6; l++) {
        layerprep_k<<<28416, 256, 0, stream>>>(
            wq + (size_t)l * 589824, wk + (size_t)l * 589824, wv + (size_t)l * 589824,
            wo + (size_t)l * 589824, rel_emb + (size_t)l * 152832,
            ff1_w + (size_t)l * 2359296, ff2_w + (size_t)l * 2359296,
            Wqkv, Wo, Relp, F1, F2);
        // fused QKV
        mgemm_k<false, false, false, false, true><<<dim3(18, 32, 1), 256, 0, stream>>>(
            xb, Wqkv, nullptr, nullptr, nullptr, qkv, 768, 768, 768, 2304, 2304,
            1, 0, 0, 0, 0, 0, 0);
        vt_k<<<dim3(16, 4, 64), 256, 0, stream>>>(qkv, vt);
        // rel logits (padded N=256): relb[h][4096][256]
        mgemm_k<false, false, false, true, false><<<dim3(2, 32, 8), 256, 0, stream>>>(
            qkv, Relp, nullptr, nullptr, relb, nullptr, 96, 2304, 96, 256, 256,
            1, 96, 0, 24576, 0, 1048576, 0);
        qkrel_k<<<dim3(4, 4, 64), 256, 0, stream>>>(qkv, relb, lg);
        softmax_k<<<32768, 256, 0, stream>>>(lg);
        // PV: probs (bf16 in-place rows of lg, lda=1024) x vt
        mgemm_k<false, false, false, false, true><<<dim3(1, 4, 64), 256, 0, stream>>>(
            (const bf16*)lg, vt, nullptr, nullptr, nullptr, atno, 512, 1024, 512, 768, 96,
            8, 4194304, 524288, 524288, 65536, 393216, 96);
        // out-proj + residual
        mgemm_k<false, true, false, true, false><<<dim3(6, 32, 1), 256, 0, stream>>>(
            atno, Wo, nullptr, xf, tmp, nullptr, 768, 768, 768, 768, 768,
            1, 0, 0, 0, 0, 0, 0);
        ln2_k<<<4096, 256, 0, stream>>>(tmp, ln1_g + l * 768, ln1_b + l * 768, xf, xb);
        // FF
        mgemm_k<true, false, true, false, true><<<dim3(24, 32, 1), 256, 0, stream>>>(
            xb, F1, ff1_b + l * 3072, nullptr, nullptr, ffh, 768, 768, 768, 3072, 3072,
            1, 0, 0, 0, 0, 0, 0);
        mgemm_k<true, true, false, true, false><<<dim3(6, 32, 1), 256, 0, stream>>>(
            ffh, F2, ff2_b + l * 768, xf, tmp, nullptr, 3072, 3072, 3072, 768, 768,
            1, 0, 0, 0, 0, 0, 0);
        ln2_k<<<4096, 256, 0, stream>>>(tmp, ln2_g + l * 768, ln2_b + l * 768, xf, xb);
    }

    // output head
    mgemm_k<true, false, false, true, false><<<dim3(8, 32, 1), 256, 0, stream>>>(
        xb, Wout, w_out_b, nullptr, out, nullptr, 768, 768, 768, 1024, 1024,
        1, 0, 0, 0, 0, 0, 0);
}

// Round 3
// 2591.219 us; speedup vs baseline: 4.2745x; 1.1881x over previous
//
#include <hip/hip_runtime.h>
#include <math.h>

typedef __bf16 bf16;
typedef bf16 bf16x8 __attribute__((ext_vector_type(8)));
typedef bf16 bf16x4 __attribute__((ext_vector_type(4)));
typedef float f32x4 __attribute__((ext_vector_type(4)));
#define EPSF 1e-5f

__device__ __forceinline__ void ldg_lds16(const bf16* g, bf16* l) {
    __builtin_amdgcn_global_load_lds((const __attribute__((address_space(1))) void*)g,
                                     (__attribute__((address_space(3))) void*)l, 16, 0, 0);
}

// bijective XCD-chunked block swizzle (m204): blocks orig%8==k get contiguous tile range
__device__ __forceinline__ int xcd_swz(int orig, int nwg) {
    int xcd = orig & 7, base = orig >> 3;
    int q = nwg >> 3, r = nwg & 7;
    return (xcd < r ? xcd * (q + 1) : r * (q + 1) + (xcd - r) * q) + base;
}

// ===================== generic bf16 MFMA GEMM: C = A[M,K] x B[N,K]^T =====================
// 128x128 tile, BK=32, 256 thr = 4 waves (2x2). Double-buffered LDS (T3-minimum pipeline).
// BAND: restrict K-loop to attention band [m0-99, m0+226] (PV use; K=j index).
template<bool BIAS, bool RESF, bool RELU, bool WF, bool WB, bool BAND>
__global__ __launch_bounds__(256) void mgemm_k(
    const bf16* __restrict__ A, const bf16* __restrict__ B,
    const float* __restrict__ bias, const float* __restrict__ resf,
    float* __restrict__ Cf, bf16* __restrict__ Cb,
    int K, int lda, int ldb, int ldc, int Nstore,
    int Z2, long long sA1, long long sA2, long long sB1, long long sB2,
    long long sC1, long long sC2)
{
    int z = blockIdx.z;
    int z1 = z / Z2, z2 = z - z1 * Z2;
    A += z1 * sA1 + z2 * sA2;
    B += z1 * sB1 + z2 * sB2;
    long long coff = z1 * sC1 + z2 * sC2;

    int bx = blockIdx.x, by = blockIdx.y;
    int nwg = gridDim.x * gridDim.y;
    if ((nwg & 7) == 0 && nwg >= 16) {
        int id = xcd_swz(by * gridDim.x + bx, nwg);
        bx = id % gridDim.x; by = id / gridDim.x;
    }

    __shared__ __align__(16) bf16 As[8192];
    __shared__ __align__(16) bf16 Bs[8192];
    int tid = threadIdx.x, wid = tid >> 6, lane = tid & 63;
    int m0 = by * 128, n0 = bx * 128;
    int wr = wid >> 1, wc = wid & 1;
    int lrow = lane & 15, lk8 = (lane >> 4) * 8;
    int srow = wid * 32 + (lane >> 2);
    int scol = (lane & 3) * 8;
    f32x4 acc[4][4] = {};

    int ktlo = 0, nt;
    if (BAND) {
        int lo = m0 - 99; if (lo < 0) lo = 0;
        ktlo = (lo >> 5) << 5;
        int hi = ((m0 + 226) >> 5) * 32 + 32;
        if (hi > K) hi = K;
        nt = (hi - ktlo) >> 5;
    } else {
        nt = K >> 5;
    }

#define STAGE_AB(cur, kt) do { \
    ldg_lds16(A + (size_t)(m0 + srow) * lda + (kt) + scol, As + (cur) * 4096 + wid * 1024); \
    ldg_lds16(A + (size_t)(m0 + srow + 16) * lda + (kt) + scol, As + (cur) * 4096 + wid * 1024 + 512); \
    ldg_lds16(B + (size_t)(n0 + srow) * ldb + (kt) + scol, Bs + (cur) * 4096 + wid * 1024); \
    ldg_lds16(B + (size_t)(n0 + srow + 16) * ldb + (kt) + scol, Bs + (cur) * 4096 + wid * 1024 + 512); \
} while (0)

    STAGE_AB(0, ktlo);
    __syncthreads();
    for (int t = 0; t < nt; t++) {
        int cur = t & 1;
        if (t + 1 < nt) STAGE_AB(cur ^ 1, ktlo + (t + 1) * 32);
        bf16x8 af[4], bfr[4];
#pragma unroll
        for (int i = 0; i < 4; i++) {
            af[i]  = *(const bf16x8*)(As + cur * 4096 + (wr * 64 + i * 16 + lrow) * 32 + lk8);
            bfr[i] = *(const bf16x8*)(Bs + cur * 4096 + (wc * 64 + i * 16 + lrow) * 32 + lk8);
        }
#pragma unroll
        for (int i = 0; i < 4; i++)
#pragma unroll
            for (int j = 0; j < 4; j++)
                acc[i][j] = __builtin_amdgcn_mfma_f32_16x16x32_bf16(af[i], bfr[j], acc[i][j], 0, 0, 0);
        __syncthreads();
    }
#undef STAGE_AB

    int mtop = m0 + wr * 64 + (lane >> 4) * 4;
    int ntop = n0 + wc * 64 + lrow;
#pragma unroll
    for (int mi = 0; mi < 4; mi++) {
#pragma unroll
        for (int r = 0; r < 4; r++) {
            int m = mtop + mi * 16 + r;
            long long ro = coff + (long long)m * ldc;
#pragma unroll
            for (int ni = 0; ni < 4; ni++) {
                int n = ntop + ni * 16;
                float v = acc[mi][ni][r];
                if (BIAS) v += bias[n];
                if (RESF) v += resf[ro + n];
                if (RELU) v = fmaxf(v, 0.f);
                if (n < Nstore) {
                    if (WF) Cf[ro + n] = v;
                    if (WB) Cb[ro + n] = (bf16)v;
                }
            }
        }
    }
}

// ===================== conv1d as MFMA GEMM (double-buffered, XCD-swizzled) =====================
template<bool RES, bool RELU>
__global__ __launch_bounds__(256) void conv_k(
    const bf16* __restrict__ in, const bf16* __restrict__ w,
    const float* __restrict__ scsh, const bf16* __restrict__ res, bf16* __restrict__ out,
    int KK, int stride, int rowoff, long long instrideB, long long outstrideB, int outoff,
    long long resstrideB)
{
    int z = blockIdx.z;
    int bx = blockIdx.x, by = blockIdx.y;
    int nwg = gridDim.x * gridDim.y;
    if ((nwg & 7) == 0 && nwg >= 16) {
        int id = xcd_swz(by * gridDim.x + bx, nwg);
        bx = id % gridDim.x; by = id / gridDim.x;
    }
    int n0 = bx * 128, m0 = by * 128;
    __shared__ __align__(16) bf16 As[8192];
    __shared__ __align__(16) bf16 Bs[8192];
    int tid = threadIdx.x, wid = tid >> 6, lane = tid & 63;
    int wr = wid >> 1, wc = wid & 1;
    int lrow = lane & 15, lk8 = (lane >> 4) * 8;
    int srow = wid * 32 + (lane >> 2);
    int scol = (lane & 3) * 8;
    const bf16* inz = in + (size_t)z * instrideB;
    f32x4 acc[4][4] = {};
    int nt = KK >> 5;

#define STAGE_CV(cur, kt) do { \
    int kq_ = (kt) / 768; \
    int ic0_ = (kt) - kq_ * 768; \
    ldg_lds16(inz + (size_t)((m0 + srow) * stride + kq_ + rowoff) * 768 + ic0_ + scol, As + (cur) * 4096 + wid * 1024); \
    ldg_lds16(inz + (size_t)((m0 + srow + 16) * stride + kq_ + rowoff) * 768 + ic0_ + scol, As + (cur) * 4096 + wid * 1024 + 512); \
    ldg_lds16(w + (size_t)(n0 + srow) * KK + (kt) + scol, Bs + (cur) * 4096 + wid * 1024); \
    ldg_lds16(w + (size_t)(n0 + srow + 16) * KK + (kt) + scol, Bs + (cur) * 4096 + wid * 1024 + 512); \
} while (0)

    STAGE_CV(0, 0);
    __syncthreads();
    for (int t = 0; t < nt; t++) {
        int cur = t & 1;
        if (t + 1 < nt) STAGE_CV(cur ^ 1, (t + 1) * 32);
        bf16x8 af[4], bfr[4];
#pragma unroll
        for (int i = 0; i < 4; i++) {
            af[i]  = *(const bf16x8*)(As + cur * 4096 + (wr * 64 + i * 16 + lrow) * 32 + lk8);
            bfr[i] = *(const bf16x8*)(Bs + cur * 4096 + (wc * 64 + i * 16 + lrow) * 32 + lk8);
        }
#pragma unroll
        for (int i = 0; i < 4; i++)
#pragma unroll
            for (int j = 0; j < 4; j++)
                acc[i][j] = __builtin_amdgcn_mfma_f32_16x16x32_bf16(af[i], bfr[j], acc[i][j], 0, 0, 0);
        __syncthreads();
    }
#undef STAGE_CV

    bf16* outz = out + (size_t)z * outstrideB + (size_t)outoff * 768;
    const bf16* resz = res + (RES ? (size_t)z * resstrideB : 0);
    int mtop = m0 + wr * 64 + (lane >> 4) * 4;
    int ntop = n0 + wc * 64 + lrow;
#pragma unroll
    for (int mi = 0; mi < 4; mi++) {
#pragma unroll
        for (int r = 0; r < 4; r++) {
            int m = mtop + mi * 16 + r;
#pragma unroll
            for (int ni = 0; ni < 4; ni++) {
                int n = ntop + ni * 16;
                float v = acc[mi][ni][r] * scsh[n] + scsh[768 + n];
                if (RES) v += (float)resz[(size_t)m * 768 + n];
                if (RELU) v = fmaxf(v, 0.f);
                outz[(size_t)m * 768 + n] = (bf16)v;
            }
        }
    }
}

// ===================== QK^T*scale + banded rel-pos + mask — only alive tiles launched =====================
__device__ const int qk_ti[10] = {0, 0, 1, 1, 1, 2, 2, 2, 3, 3};
__device__ const int qk_tj[10] = {0, 1, 0, 1, 2, 1, 2, 3, 2, 3};

__global__ __launch_bounds__(256) void qkrel_k(
    const bf16* __restrict__ qkv, const float* __restrict__ relb, float* __restrict__ lg)
{
    int z = blockIdx.z, b = z >> 3, h = z & 7;
    int i0 = qk_ti[blockIdx.x] * 128, j0 = qk_tj[blockIdx.x] * 128;
    long long lgbase = (long long)z * 262144;
    const bf16* Aq = qkv + (size_t)b * 512 * 2304 + h * 96;
    const bf16* Bk = Aq + 768;
    __shared__ __align__(16) bf16 As[8192];
    __shared__ __align__(16) bf16 Bs[8192];
    int tid = threadIdx.x, wid = tid >> 6, lane = tid & 63;
    int wr = wid >> 1, wc = wid & 1;
    int lrow = lane & 15, lk8 = (lane >> 4) * 8;
    int srow = wid * 32 + (lane >> 2);
    int scol = (lane & 3) * 8;
    f32x4 acc[4][4] = {};

#define STAGE_QK(cur, kt) do { \
    ldg_lds16(Aq + (size_t)(i0 + srow) * 2304 + (kt) + scol, As + (cur) * 4096 + wid * 1024); \
    ldg_lds16(Aq + (size_t)(i0 + srow + 16) * 2304 + (kt) + scol, As + (cur) * 4096 + wid * 1024 + 512); \
    ldg_lds16(Bk + (size_t)(j0 + srow) * 2304 + (kt) + scol, Bs + (cur) * 4096 + wid * 1024); \
    ldg_lds16(Bk + (size_t)(j0 + srow + 16) * 2304 + (kt) + scol, Bs + (cur) * 4096 + wid * 1024 + 512); \
} while (0)

    STAGE_QK(0, 0);
    __syncthreads();
    for (int t = 0; t < 3; t++) {
        int cur = t & 1;
        if (t + 1 < 3) STAGE_QK(cur ^ 1, (t + 1) * 32);
        bf16x8 af[4], bfr[4];
#pragma unroll
        for (int i = 0; i < 4; i++) {
            af[i]  = *(const bf16x8*)(As + cur * 4096 + (wr * 64 + i * 16 + lrow) * 32 + lk8);
            bfr[i] = *(const bf16x8*)(Bs + cur * 4096 + (wc * 64 + i * 16 + lrow) * 32 + lk8);
        }
#pragma unroll
        for (int i = 0; i < 4; i++)
#pragma unroll
            for (int j = 0; j < 4; j++)
                acc[i][j] = __builtin_amdgcn_mfma_f32_16x16x32_bf16(af[i], bfr[j], acc[i][j], 0, 0, 0);
        __syncthreads();
    }
#undef STAGE_QK

    const float sc = 0.10206207261596577f;  // 1/sqrt(96)
    int itop = i0 + wr * 64 + (lane >> 4) * 4;
    int jtop = j0 + wc * 64 + lrow;
#pragma unroll
    for (int mi = 0; mi < 4; mi++) {
#pragma unroll
        for (int r = 0; r < 4; r++) {
            int i = itop + mi * 16 + r;
            const float* rrow = relb + ((long long)h * 4096 + b * 512 + i) * 256;
#pragma unroll
            for (int ni = 0; ni < 4; ni++) {
                int j = jtop + ni * 16;
                float v = acc[mi][ni][r] * sc;
                int idx = j - i + 99;
                v += (idx >= 0 && idx < 199) ? rrow[idx] : -1e8f;
                lg[lgbase + (long long)i * 512 + j] = v;
            }
        }
    }
}

// ===================== banded row softmax fp32 -> bf16 in place =====================
// Row i: live cols are [i-99, i+99]; read only window, write full 512 (zeros outside).
__global__ __launch_bounds__(256) void softmax_k(float* __restrict__ lg)
{
    __shared__ float red1[4];
    __shared__ float red2[4];
    size_t r = blockIdx.x;
    int i = (int)(r & 511);
    int jlo = i - 99; if (jlo < 0) jlo = 0;
    int jhi = i + 100; if (jhi > 512) jhi = 512;
    float* p = lg + r * 512;
    int tid = threadIdx.x;
    int j = jlo + tid;
    bool act = j < jhi;
    float v = act ? p[j] : -1e30f;
    float m = v;
#pragma unroll
    for (int off = 32; off; off >>= 1) m = fmaxf(m, __shfl_xor(m, off));
    if ((tid & 63) == 0) red1[tid >> 6] = m;
    __syncthreads();
    m = fmaxf(fmaxf(red1[0], red1[1]), fmaxf(red1[2], red1[3]));
    float e = act ? expf(v - m) : 0.f;
    float s = e;
#pragma unroll
    for (int off = 32; off; off >>= 1) s += __shfl_xor(s, off);
    if ((tid & 63) == 0) red2[tid >> 6] = s;
    __syncthreads();
    float inv = 1.f / (red2[0] + red2[1] + red2[2] + red2[3]);
    bf16* pb = (bf16*)p;
    if (act) pb[j] = (bf16)(e * inv);
#pragma unroll
    for (int c = tid; c < 512; c += 256)
        if (c < jlo || c >= jhi) pb[c] = (bf16)0.f;
}

// ===================== LayerNorm fp32 in, fp32 + bf16 out =====================
__global__ __launch_bounds__(256) void ln2_k(const float* __restrict__ in,
                                             const float* __restrict__ g,
                                             const float* __restrict__ b,
                                             float* __restrict__ xf, bf16* __restrict__ xb)
{
    __shared__ float red1[4];
    __shared__ float red2[4];
    int r = blockIdx.x, tid = threadIdx.x;
    const float* p = in + (size_t)r * 768;
    float x0 = p[tid], x1 = p[tid + 256], x2 = p[tid + 512];
    float s = x0 + x1 + x2;
#pragma unroll
    for (int off = 32; off; off >>= 1) s += __shfl_xor(s, off);
    if ((tid & 63) == 0) red1[tid >> 6] = s;
    __syncthreads();
    float mu = (red1[0] + red1[1] + red1[2] + red1[3]) * (1.f / 768.f);
    float d0 = x0 - mu, d1 = x1 - mu, d2 = x2 - mu;
    float sq = d0 * d0 + d1 * d1 + d2 * d2;
#pragma unroll
    for (int off = 32; off; off >>= 1) sq += __shfl_xor(sq, off);
    if ((tid & 63) == 0) red2[tid >> 6] = sq;
    __syncthreads();
    float rstd = rsqrtf((red2[0] + red2[1] + red2[2] + red2[3]) * (1.f / 768.f) + EPSF);
    float o0 = g[tid] * d0 * rstd + b[tid];
    float o1 = g[tid + 256] * d1 * rstd + b[tid + 256];
    float o2 = g[tid + 512] * d2 * rstd + b[tid + 512];
    size_t base = (size_t)r * 768;
    xf[base + tid] = o0;       xb[base + tid] = (bf16)o0;
    xf[base + tid + 256] = o1; xb[base + tid + 256] = (bf16)o1;
    xf[base + tid + 512] = o2; xb[base + tid + 512] = (bf16)o2;
}

// ===================== resblock1 front (CIN=8) -> bf16 t-major =====================
__global__ __launch_bounds__(256) void rb1_front_k(
    const float* __restrict__ xr, const float* __restrict__ c1w, const float* __restrict__ rw,
    const float* __restrict__ scsh0, const float* __restrict__ scsh1,
    bf16* __restrict__ h1, bf16* __restrict__ res1)
{
    int t = blockIdx.x, b = blockIdx.y, tid = threadIdx.x;
    const float* xb = xr + (size_t)b * 4096 * 8;
    float xv[3][8];
#pragma unroll
    for (int k = 0; k < 3; k++) {
        int pos = 2 * t + k - 1;
        bool ok = (unsigned)pos < 4096u;
        const float* xp = xb + (size_t)pos * 8;
#pragma unroll
        for (int c = 0; c < 8; c++) xv[k][c] = ok ? xp[c] : 0.f;
    }
#pragma unroll
    for (int rep = 0; rep < 3; rep++) {
        int o = rep * 256 + tid;
        float conv = 0.f;
        const float* wp = c1w + (size_t)o * 24;
#pragma unroll
        for (int c = 0; c < 8; c++)
#pragma unroll
            for (int k = 0; k < 3; k++) conv = fmaf(wp[c * 3 + k], xv[k][c], conv);
        float hv = fmaxf(conv * scsh0[o] + scsh0[768 + o], 0.f);
        h1[((size_t)b * 2050 + t + 1) * 768 + o] = (bf16)hv;
        float cr = 0.f;
        const float* rp = rw + (size_t)o * 8;
#pragma unroll
        for (int c = 0; c < 8; c++) cr = fmaf(rp[c], xv[1][c], cr);
        res1[((size_t)b * 2048 + t) * 768 + o] = (bf16)(cr * scsh1[o] + scsh1[768 + o]);
    }
}

// ===================== small prep kernels =====================
__global__ void bnprep_k(const float* __restrict__ bn, const float* __restrict__ cb,
                         float* __restrict__ scsh)
{
    int i = blockIdx.x * 256 + threadIdx.x;
    if (i >= 768) return;
    float g = bn[i], be = bn[768 + i], m = bn[1536 + i], v = bn[2304 + i];
    float sc = g * rsqrtf(v + EPSF);
    scsh[i] = sc;
    scsh[768 + i] = (cb[i] - m) * sc + be;
}

__global__ void zeropad_k(bf16* __restrict__ buf, int T)
{
    int i = blockIdx.x * 256 + threadIdx.x;
    if (i >= 768) return;
    int row = blockIdx.y ? (T + 1) : 0;
    buf[((size_t)blockIdx.z * (T + 2) + row) * 768 + i] = (bf16)0.f;
}

__global__ void rep3_k(const float* __restrict__ w, bf16* __restrict__ wr)
{
    long long i = (long long)blockIdx.x * 256 + threadIdx.x;
    if (i >= 1769472) return;
    int o = i / 2304, k = i - (long long)o * 2304;
    int kq = k / 768, ic = k - kq * 768;
    wr[i] = (bf16)w[((long long)o * 768 + ic) * 3 + kq];
}

__global__ void cast4_k(const float* __restrict__ s, bf16* __restrict__ d, int n4)
{
    int i = blockIdx.x * 256 + threadIdx.x;
    if (i >= n4) return;
    float4 v = ((const float4*)s)[i];
    bf16x4 o = {(bf16)v.x, (bf16)v.y, (bf16)v.z, (bf16)v.w};
    ((bf16x4*)d)[i] = o;
}

// per-layer weight prep: Wqkv[2304][768], Wo[768][768], Rel[8][256][96] pad, F1/F2 casts
__global__ void layerprep_k(const float* __restrict__ wq, const float* __restrict__ wk,
                            const float* __restrict__ wv, const float* __restrict__ wo,
                            const float* __restrict__ rel,
                            const float* __restrict__ ff1, const float* __restrict__ ff2,
                            bf16* __restrict__ Wqkv, bf16* __restrict__ Wo,
                            bf16* __restrict__ Rel, bf16* __restrict__ F1, bf16* __restrict__ F2)
{
    long long i = (long long)blockIdx.x * 256 + threadIdx.x;
    const long long S0 = 1769472, S1 = 589824, S2 = 196608, S3 = 2359296;
    if (i < S0) {
        int n = i / 768, k = i - (long long)n * 768;
        int sel = n / 768, hq = n - sel * 768;
        int h = hq / 96, q = hq - h * 96;
        const float* src = sel == 0 ? wq : (sel == 1 ? wk : wv);
        Wqkv[i] = (bf16)src[((long long)h * 768 + k) * 96 + q];
    } else if (i < S0 + S1) {
        long long j = i - S0;
        int n = j / 768, kk = j - (long long)n * 768;
        Wo[j] = (bf16)wo[(long long)kk * 768 + n];
    } else if (i < S0 + S1 + S2) {
        long long j = i - S0 - S1;
        int h = j / 24576, rest = j - (long long)h * 24576;
        int rr = rest / 96, q = rest - rr * 96;
        Rel[j] = rr < 199 ? (bf16)rel[((long long)h * 199 + rr) * 96 + q] : (bf16)0.f;
    } else if (i < S0 + S1 + S2 + S3) {
        long long j = i - S0 - S1 - S2;
        F1[j] = (bf16)ff1[j];
    } else {
        long long j = i - S0 - S1 - S2 - S3;
        F2[j] = (bf16)ff2[j];
    }
}

// vt[z=(b*8+h)][q 0..127][t 0..511] = v part of qkv, rows 96..127 zero
__global__ __launch_bounds__(256) void vt_k(const bf16* __restrict__ qkv, bf16* __restrict__ vt)
{
    int z = blockIdx.z, b = z >> 3, h = z & 7;
    int t0 = blockIdx.x * 32, q0 = blockIdx.y * 32;
    __shared__ bf16 sm[32][33];
    int tx = threadIdx.x & 31, ty = threadIdx.x >> 5;
#pragma unroll
    for (int s = 0; s < 4; s++) {
        int t = t0 + ty + s * 8, q = q0 + tx;
        sm[ty + s * 8][tx] = (q < 96) ? qkv[((size_t)b * 512 + t) * 2304 + 1536 + h * 96 + q]
                                      : (bf16)0.f;
    }
    __syncthreads();
#pragma unroll
    for (int s = 0; s < 4; s++) {
        int q = q0 + ty + s * 8;
        vt[((size_t)z * 128 + q) * 512 + t0 + tx] = sm[tx][ty + s * 8];
    }
}

// ===================== host launch =====================
extern "C" void kernel_launch(void* const* d_in, const int* in_sizes, int n_in,
                              void* d_out, int out_size, void* d_ws, size_t ws_size,
                              hipStream_t stream)
{
    const float* x_raw    = (const float*)d_in[0];
    const float* rb1_c1w  = (const float*)d_in[1];
    const float* rb1_c1b  = (const float*)d_in[2];
    const float* rb1_bn1  = (const float*)d_in[3];
    const float* rb1_c2w  = (const float*)d_in[4];
    const float* rb1_c2b  = (const float*)d_in[5];
    const float* rb1_bn2  = (const float*)d_in[6];
    const float* rb1_rw   = (const float*)d_in[7];
    const float* rb1_rb   = (const float*)d_in[8];
    const float* rb1_bnr  = (const float*)d_in[9];
    const float* rb23_c1w = (const float*)d_in[10];
    const float* rb23_c1b = (const float*)d_in[11];
    const float* rb23_bn1 = (const float*)d_in[12];
    const float* rb23_c2w = (const float*)d_in[13];
    const float* rb23_c2b = (const float*)d_in[14];
    const float* rb23_bn2 = (const float*)d_in[15];
    const float* rb23_rw  = (const float*)d_in[16];
    const float* rb23_rb  = (const float*)d_in[17];
    const float* rb23_bnr = (const float*)d_in[18];
    const float* w_in_w   = (const float*)d_in[19];
    const float* w_in_b   = (const float*)d_in[20];
    const float* wq       = (const float*)d_in[21];
    const float* wk       = (const float*)d_in[22];
    const float* wv       = (const float*)d_in[23];
    const float* wo       = (const float*)d_in[24];
    const float* rel_emb  = (const float*)d_in[25];
    const float* ln1_g    = (const float*)d_in[26];
    const float* ln1_b    = (const float*)d_in[27];
    const float* ln2_g    = (const float*)d_in[28];
    const float* ln2_b    = (const float*)d_in[29];
    const float* ff1_w    = (const float*)d_in[30];
    const float* ff1_b    = (const float*)d_in[31];
    const float* ff2_w    = (const float*)d_in[32];
    const float* ff2_b    = (const float*)d_in[33];
    const float* w_out_w  = (const float*)d_in[34];
    const float* w_out_b  = (const float*)d_in[35];
    float* out = (float*)d_out;

    char* W = (char*)d_ws;
    bf16*  h1buf  = (bf16*)(W + 0);           // h1/h2/h3 (padded t-major)
    bf16*  resbuf = (bf16*)(W + 26000000);    // res1/r2/r3
    bf16*  xbuf   = (bf16*)(W + 52000000);    // x1/x2/x3
    float* lg     = (float*)(W + 0);          // 67.1MB logits (transformer phase)
    bf16*  wc3    = (bf16*)(W + 78000000);
    bf16*  wc1    = (bf16*)(W + 82000000);
    float* scsh   = (float*)(W + 84000000);   // 9 slots of [2][768]
    float* xf     = (float*)(W + 85000000);
    bf16*  xb     = (bf16*)(W + 98000000);
    bf16*  qkv    = (bf16*)(W + 105000000);
    bf16*  vt     = (bf16*)(W + 124000000);
    float* relb   = (float*)(W + 133000000);  // shares region with ffh
    bf16*  ffh    = (bf16*)(W + 133000000);
    bf16*  atno   = (bf16*)(W + 167000000);
    float* tmp    = (float*)(W + 174000000);
    bf16*  Wqkv   = (bf16*)(W + 187000000);
    bf16*  Wo     = (bf16*)(W + 191000000);
    bf16*  F1     = (bf16*)(W + 193000000);
    bf16*  F2     = (bf16*)(W + 198000000);
    bf16*  Relp   = (bf16*)(W + 203000000);
    bf16*  Wout   = (bf16*)(W + 204000000);
    bf16*  Winw   = (bf16*)(W + 206000000);

    // ---- BN fold ----
    bnprep_k<<<3, 256, 0, stream>>>(rb1_bn1, rb1_c1b, scsh + 0 * 1536);
    bnprep_k<<<3, 256, 0, stream>>>(rb1_bnr, rb1_rb,  scsh + 1 * 1536);
    bnprep_k<<<3, 256, 0, stream>>>(rb1_bn2, rb1_c2b, scsh + 2 * 1536);
    bnprep_k<<<3, 256, 0, stream>>>(rb23_bn1, rb23_c1b, scsh + 3 * 1536);
    bnprep_k<<<3, 256, 0, stream>>>(rb23_bnr, rb23_rb,  scsh + 4 * 1536);
    bnprep_k<<<3, 256, 0, stream>>>(rb23_bn2, rb23_c2b, scsh + 5 * 1536);
    bnprep_k<<<3, 256, 0, stream>>>(rb23_bn1 + 3072, rb23_c1b + 768, scsh + 6 * 1536);
    bnprep_k<<<3, 256, 0, stream>>>(rb23_bnr + 3072, rb23_rb + 768,  scsh + 7 * 1536);
    bnprep_k<<<3, 256, 0, stream>>>(rb23_bn2 + 3072, rb23_c2b + 768, scsh + 8 * 1536);

    // ---- conv stack, t-major bf16, T 4096->2048->1024->512 ----
    rb1_front_k<<<dim3(2048, 8), 256, 0, stream>>>(x_raw, rb1_c1w, rb1_rw,
                                                   scsh, scsh + 1536, h1buf, resbuf);
    zeropad_k<<<dim3(3, 2, 8), 256, 0, stream>>>(h1buf, 2048);
    rep3_k<<<6912, 256, 0, stream>>>(rb1_c2w, wc3);
    conv_k<true, true><<<dim3(6, 16, 8), 256, 0, stream>>>(
        h1buf, wc3, scsh + 2 * 1536, resbuf, xbuf, 2304, 1, 0,
        (long long)2050 * 768, (long long)2050 * 768, 1, (long long)2048 * 768);
    zeropad_k<<<dim3(3, 2, 8), 256, 0, stream>>>(xbuf, 2048);
    // rb2
    rep3_k<<<6912, 256, 0, stream>>>(rb23_c1w, wc3);
    conv_k<false, true><<<dim3(6, 8, 8), 256, 0, stream>>>(
        xbuf, wc3, scsh + 3 * 1536, nullptr, h1buf, 2304, 2, 0,
        (long long)2050 * 768, (long long)1026 * 768, 1, 0);
    zeropad_k<<<dim3(3, 2, 8), 256, 0, stream>>>(h1buf, 1024);
    cast4_k<<<576, 256, 0, stream>>>(rb23_rw, wc1, 147456);
    conv_k<false, false><<<dim3(6, 8, 8), 256, 0, stream>>>(
        xbuf, wc1, scsh + 4 * 1536, nullptr, resbuf, 768, 2, 1,
        (long long)2050 * 768, (long long)1024 * 768, 0, 0);
    rep3_k<<<6912, 256, 0, stream>>>(rb23_c2w, wc3);
    conv_k<true, true><<<dim3(6, 8, 8), 256, 0, stream>>>(
        h1buf, wc3, scsh + 5 * 1536, resbuf, xbuf, 2304, 1, 0,
        (long long)1026 * 768, (long long)1026 * 768, 1, (long long)1024 * 768);
    zeropad_k<<<dim3(3, 2, 8), 256, 0, stream>>>(xbuf, 1024);
    // rb3
    rep3_k<<<6912, 256, 0, stream>>>(rb23_c1w + 1769472, wc3);
    conv_k<false, true><<<dim3(6, 4, 8), 256, 0, stream>>>(
        xbuf, wc3, scsh + 6 * 1536, nullptr, h1buf, 2304, 2, 0,
        (long long)1026 * 768, (long long)514 * 768, 1, 0);
    zeropad_k<<<dim3(3, 2, 8), 256, 0, stream>>>(h1buf, 512);
    cast4_k<<<576, 256, 0, stream>>>(rb23_rw + 589824, wc1, 147456);
    conv_k<false, false><<<dim3(6, 4, 8), 256, 0, stream>>>(
        xbuf, wc1, scsh + 7 * 1536, nullptr, resbuf, 768, 2, 1,
        (long long)1026 * 768, (long long)512 * 768, 0, 0);
    rep3_k<<<6912, 256, 0, stream>>>(rb23_c2w + 1769472, wc3);
    conv_k<true, true><<<dim3(6, 4, 8), 256, 0, stream>>>(
        h1buf, wc3, scsh + 8 * 1536, resbuf, xbuf, 2304, 1, 0,
        (long long)514 * 768, (long long)512 * 768, 0, (long long)512 * 768);
    // xbuf now = x3 [4096][768] bf16 (t-major, unpadded) = transformer input

    // ---- transformer ----
    cast4_k<<<576, 256, 0, stream>>>(w_in_w, Winw, 147456);
    cast4_k<<<768, 256, 0, stream>>>(w_out_w, Wout, 196608);
    mgemm_k<true, false, false, true, true, false><<<dim3(6, 32, 1), 256, 0, stream>>>(
        xbuf, Winw, w_in_b, nullptr, xf, xb, 768, 768, 768, 768, 768, 1, 0, 0, 0, 0, 0, 0);

    for (int l = 0; l < 6; l++) {
        layerprep_k<<<28416, 256, 0, stream>>>(
            wq + (size_t)l * 589824, wk + (size_t)l * 589824, wv + (size_t)l * 589824,
            wo + (size_t)l * 589824, rel_emb + (size_t)l * 152832,
            ff1_w + (size_t)l * 2359296, ff2_w + (size_t)l * 2359296,
            Wqkv, Wo, Relp, F1, F2);
        // fused QKV
        mgemm_k<false, false, false, false, true, false><<<dim3(18, 32, 1), 256, 0, stream>>>(
            xb, Wqkv, nullptr, nullptr, nullptr, qkv, 768, 768, 768, 2304, 2304,
            1, 0, 0, 0, 0, 0, 0);
        vt_k<<<dim3(16, 4, 64), 256, 0, stream>>>(qkv, vt);
        // rel logits (padded N=256): relb[h][4096][256]
        mgemm_k<false, false, false, true, false, false><<<dim3(2, 32, 8), 256, 0, stream>>>(
            qkv, Relp, nullptr, nullptr, relb, nullptr, 96, 2304, 96, 256, 256,
            1, 96, 0, 24576, 0, 1048576, 0);
        qkrel_k<<<dim3(10, 1, 64), 256, 0, stream>>>(qkv, relb, lg);
        softmax_k<<<32768, 256, 0, stream>>>(lg);
        // PV: probs (bf16 in-place rows of lg, lda=1024) x vt, band-restricted K
        mgemm_k<false, false, false, false, true, true><<<dim3(1, 4, 64), 256, 0, stream>>>(
            (const bf16*)lg, vt, nullptr, nullptr, nullptr, atno, 512, 1024, 512, 768, 96,
            8, 4194304, 524288, 524288, 65536, 393216, 96);
        // out-proj + residual
        mgemm_k<false, true, false, true, false, false><<<dim3(6, 32, 1), 256, 0, stream>>>(
            atno, Wo, nullptr, xf, tmp, nullptr, 768, 768, 768, 768, 768,
            1, 0, 0, 0, 0, 0, 0);
        ln2_k<<<4096, 256, 0, stream>>>(tmp, ln1_g + l * 768, ln1_b + l * 768, xf, xb);
        // FF
        mgemm_k<true, false, true, false, true, false><<<dim3(24, 32, 1), 256, 0, stream>>>(
            xb, F1, ff1_b + l * 3072, nullptr, nullptr, ffh, 768, 768, 768, 3072, 3072,
            1, 0, 0, 0, 0, 0, 0);
        mgemm_k<true, true, false, true, false, false><<<dim3(6, 32, 1), 256, 0, stream>>>(
            ffh, F2, ff2_b + l * 768, xf, tmp, nullptr, 3072, 3072, 3072, 768, 768,
            1, 0, 0, 0, 0, 0, 0);
        ln2_k<<<4096, 256, 0, stream>>>(tmp, ln2_g + l * 768, ln2_b + l * 768, xf, xb);
    }

    // output head
    mgemm_k<true, false, false, true, false, false><<<dim3(8, 32, 1), 256, 0, stream>>>(
        xb, Wout, w_out_b, nullptr, out, nullptr, 768, 768, 768, 1024, 1024,
        1, 0, 0, 0, 0, 0, 0);
}

// Round 4
// 2587.091 us; speedup vs baseline: 4.2813x; 1.0016x over previous
//
#include <hip/hip_runtime.h>
#include <math.h>

typedef __bf16 bf16;
typedef bf16 bf16x8 __attribute__((ext_vector_type(8)));
typedef bf16 bf16x4 __attribute__((ext_vector_type(4)));
typedef float f32x4 __attribute__((ext_vector_type(4)));
#define EPSF 1e-5f

__device__ __forceinline__ void ldg_lds16(const bf16* g, bf16* l) {
    __builtin_amdgcn_global_load_lds((const __attribute__((address_space(1))) void*)g,
                                     (__attribute__((address_space(3))) void*)l, 16, 0, 0);
}

// bijective XCD-chunked block swizzle (m204)
__device__ __forceinline__ int xcd_swz(int orig, int nwg) {
    int xcd = orig & 7, base = orig >> 3;
    int q = nwg >> 3, r = nwg & 7;
    return (xcd < r ? xcd * (q + 1) : r * (q + 1) + (xcd - r) * q) + base;
}

// ===================== generic bf16 MFMA GEMM: C = A[M,K] x B[N,K]^T =====================
// 128x128 tile, BK=32, 4 waves, double-buffered LDS.
// BAND: restrict K-loop to attention band (PV). ATOM: split-K via blockIdx.z, fp32 atomicAdd.
template<bool BIAS, bool RESF, bool RELU, bool WF, bool WB, bool BAND, bool ATOM = false>
__global__ __launch_bounds__(256) void mgemm_k(
    const bf16* __restrict__ A, const bf16* __restrict__ B,
    const float* __restrict__ bias, const float* __restrict__ resf,
    float* __restrict__ Cf, bf16* __restrict__ Cb,
    int K, int lda, int ldb, int ldc, int Nstore,
    int Z2, long long sA1, long long sA2, long long sB1, long long sB2,
    long long sC1, long long sC2, int kchunks)
{
    int z = blockIdx.z, kc = 0;
    if (ATOM) { kc = z % kchunks; z /= kchunks; }
    int z1 = z / Z2, z2 = z - z1 * Z2;
    A += z1 * sA1 + z2 * sA2;
    B += z1 * sB1 + z2 * sB2;
    long long coff = z1 * sC1 + z2 * sC2;

    int bx = blockIdx.x, by = blockIdx.y;
    int nwg = gridDim.x * gridDim.y;
    if ((nwg & 7) == 0 && nwg >= 16) {
        int id = xcd_swz(by * gridDim.x + bx, nwg);
        bx = id % gridDim.x; by = id / gridDim.x;
    }

    __shared__ __align__(16) bf16 As[8192];
    __shared__ __align__(16) bf16 Bs[8192];
    int tid = threadIdx.x, wid = tid >> 6, lane = tid & 63;
    int m0 = by * 128, n0 = bx * 128;
    int wr = wid >> 1, wc = wid & 1;
    int lrow = lane & 15, lk8 = (lane >> 4) * 8;
    int srow = wid * 32 + (lane >> 2);
    int scol = (lane & 3) * 8;
    f32x4 acc[4][4] = {};

    int Klen = ATOM ? (K / kchunks) : K;
    int ktlo, nt;
    if (BAND) {
        int lo = m0 - 99; if (lo < 0) lo = 0;
        ktlo = (lo >> 5) << 5;
        int hi = ((m0 + 226) >> 5) * 32 + 32;
        if (hi > K) hi = K;
        nt = (hi - ktlo) >> 5;
    } else {
        ktlo = ATOM ? kc * Klen : 0;
        nt = Klen >> 5;
    }

#define STAGE_AB(cur, kt) do { \
    ldg_lds16(A + (size_t)(m0 + srow) * lda + (kt) + scol, As + (cur) * 4096 + wid * 1024); \
    ldg_lds16(A + (size_t)(m0 + srow + 16) * lda + (kt) + scol, As + (cur) * 4096 + wid * 1024 + 512); \
    ldg_lds16(B + (size_t)(n0 + srow) * ldb + (kt) + scol, Bs + (cur) * 4096 + wid * 1024); \
    ldg_lds16(B + (size_t)(n0 + srow + 16) * ldb + (kt) + scol, Bs + (cur) * 4096 + wid * 1024 + 512); \
} while (0)

    STAGE_AB(0, ktlo);
    __syncthreads();
    for (int t = 0; t < nt; t++) {
        int cur = t & 1;
        if (t + 1 < nt) STAGE_AB(cur ^ 1, ktlo + (t + 1) * 32);
        bf16x8 af[4], bfr[4];
#pragma unroll
        for (int i = 0; i < 4; i++) {
            af[i]  = *(const bf16x8*)(As + cur * 4096 + (wr * 64 + i * 16 + lrow) * 32 + lk8);
            bfr[i] = *(const bf16x8*)(Bs + cur * 4096 + (wc * 64 + i * 16 + lrow) * 32 + lk8);
        }
#pragma unroll
        for (int i = 0; i < 4; i++)
#pragma unroll
            for (int j = 0; j < 4; j++)
                acc[i][j] = __builtin_amdgcn_mfma_f32_16x16x32_bf16(af[i], bfr[j], acc[i][j], 0, 0, 0);
        __syncthreads();
    }
#undef STAGE_AB

    int mtop = m0 + wr * 64 + (lane >> 4) * 4;
    int ntop = n0 + wc * 64 + lrow;
#pragma unroll
    for (int mi = 0; mi < 4; mi++) {
#pragma unroll
        for (int r = 0; r < 4; r++) {
            int m = mtop + mi * 16 + r;
            long long ro = coff + (long long)m * ldc;
#pragma unroll
            for (int ni = 0; ni < 4; ni++) {
                int n = ntop + ni * 16;
                float v = acc[mi][ni][r];
                if (BIAS && (!ATOM || kc == 0)) v += bias[n];
                if (RESF && (!ATOM || kc == 0)) v += resf[ro + n];
                if (RELU) v = fmaxf(v, 0.f);
                if (n < Nstore) {
                    if (WF) { if (ATOM) atomicAdd(&Cf[ro + n], v); else Cf[ro + n] = v; }
                    if (WB) Cb[ro + n] = (bf16)v;
                }
            }
        }
    }
}

// ===================== conv1d as MFMA GEMM (double-buffered, XCD-swizzled) =====================
template<bool RES, bool RELU>
__global__ __launch_bounds__(256) void conv_k(
    const bf16* __restrict__ in, const bf16* __restrict__ w,
    const float* __restrict__ scsh, const bf16* __restrict__ res, bf16* __restrict__ out,
    int KK, int stride, int rowoff, long long instrideB, long long outstrideB, int outoff,
    long long resstrideB, int padT)
{
    int z = blockIdx.z;
    int bx = blockIdx.x, by = blockIdx.y;
    int nwg = gridDim.x * gridDim.y;
    if ((nwg & 7) == 0 && nwg >= 16) {
        int id = xcd_swz(by * gridDim.x + bx, nwg);
        bx = id % gridDim.x; by = id / gridDim.x;
    }
    int n0 = bx * 128, m0 = by * 128;
    __shared__ __align__(16) bf16 As[8192];
    __shared__ __align__(16) bf16 Bs[8192];
    int tid = threadIdx.x, wid = tid >> 6, lane = tid & 63;
    int wr = wid >> 1, wc = wid & 1;
    int lrow = lane & 15, lk8 = (lane >> 4) * 8;
    int srow = wid * 32 + (lane >> 2);
    int scol = (lane & 3) * 8;
    const bf16* inz = in + (size_t)z * instrideB;
    f32x4 acc[4][4] = {};
    int nt = KK >> 5;

    // fold pad-row zeroing into this kernel (one block per z)
    if (padT && blockIdx.x == 0 && blockIdx.y == 0) {
        bf16* pz = out + (size_t)z * outstrideB;
        for (int i = tid; i < 768; i += 256) {
            pz[i] = (bf16)0.f;
            pz[(size_t)(padT + 1) * 768 + i] = (bf16)0.f;
        }
    }

#define STAGE_CV(cur, kt) do { \
    int kq_ = (kt) / 768; \
    int ic0_ = (kt) - kq_ * 768; \
    ldg_lds16(inz + (size_t)((m0 + srow) * stride + kq_ + rowoff) * 768 + ic0_ + scol, As + (cur) * 4096 + wid * 1024); \
    ldg_lds16(inz + (size_t)((m0 + srow + 16) * stride + kq_ + rowoff) * 768 + ic0_ + scol, As + (cur) * 4096 + wid * 1024 + 512); \
    ldg_lds16(w + (size_t)(n0 + srow) * KK + (kt) + scol, Bs + (cur) * 4096 + wid * 1024); \
    ldg_lds16(w + (size_t)(n0 + srow + 16) * KK + (kt) + scol, Bs + (cur) * 4096 + wid * 1024 + 512); \
} while (0)

    STAGE_CV(0, 0);
    __syncthreads();
    for (int t = 0; t < nt; t++) {
        int cur = t & 1;
        if (t + 1 < nt) STAGE_CV(cur ^ 1, (t + 1) * 32);
        bf16x8 af[4], bfr[4];
#pragma unroll
        for (int i = 0; i < 4; i++) {
            af[i]  = *(const bf16x8*)(As + cur * 4096 + (wr * 64 + i * 16 + lrow) * 32 + lk8);
            bfr[i] = *(const bf16x8*)(Bs + cur * 4096 + (wc * 64 + i * 16 + lrow) * 32 + lk8);
        }
#pragma unroll
        for (int i = 0; i < 4; i++)
#pragma unroll
            for (int j = 0; j < 4; j++)
                acc[i][j] = __builtin_amdgcn_mfma_f32_16x16x32_bf16(af[i], bfr[j], acc[i][j], 0, 0, 0);
        __syncthreads();
    }
#undef STAGE_CV

    bf16* outz = out + (size_t)z * outstrideB + (size_t)outoff * 768;
    const bf16* resz = res + (RES ? (size_t)z * resstrideB : 0);
    int mtop = m0 + wr * 64 + (lane >> 4) * 4;
    int ntop = n0 + wc * 64 + lrow;
#pragma unroll
    for (int mi = 0; mi < 4; mi++) {
#pragma unroll
        for (int r = 0; r < 4; r++) {
            int m = mtop + mi * 16 + r;
#pragma unroll
            for (int ni = 0; ni < 4; ni++) {
                int n = ntop + ni * 16;
                float v = acc[mi][ni][r] * scsh[n] + scsh[768 + n];
                if (RES) v += (float)resz[(size_t)m * 768 + n];
                if (RELU) v = fmaxf(v, 0.f);
                outz[(size_t)m * 768 + n] = (bf16)v;
            }
        }
    }
}

// ===================== rb1 front as one MFMA GEMM (conv1 k3s2 + res conv 1x1s2) =====================
// A[t][0..31] = xpadb[b] rows 2t..2t+3 (lda=16); B = Wrb1[1536][32] (n<768: c1, else rw)
__global__ __launch_bounds__(256) void rb1gemm_k(
    const bf16* __restrict__ xpadb, const bf16* __restrict__ Wrb1,
    const float* __restrict__ scsh0, const float* __restrict__ scshR,
    bf16* __restrict__ h1, bf16* __restrict__ res1)
{
    int b = blockIdx.z;
    int n0 = blockIdx.x * 128, m0 = blockIdx.y * 128;
    __shared__ __align__(16) bf16 As[4096];
    __shared__ __align__(16) bf16 Bs[4096];
    int tid = threadIdx.x, wid = tid >> 6, lane = tid & 63;
    int wr = wid >> 1, wc = wid & 1;
    int lrow = lane & 15, lk8 = (lane >> 4) * 8;
    int srow = wid * 32 + (lane >> 2);
    int scol = (lane & 3) * 8;

    if (blockIdx.x == 0 && blockIdx.y == 0) {  // zero h1 pad rows 0, 2049
        bf16* pz = h1 + (size_t)b * 2050 * 768;
        for (int i = tid; i < 768; i += 256) {
            pz[i] = (bf16)0.f;
            pz[(size_t)2049 * 768 + i] = (bf16)0.f;
        }
    }

    const bf16* xb = xpadb + (size_t)b * 32800;
    ldg_lds16(xb + (size_t)(m0 + srow) * 16 + scol, As + wid * 1024);
    ldg_lds16(xb + (size_t)(m0 + srow + 16) * 16 + scol, As + wid * 1024 + 512);
    ldg_lds16(Wrb1 + (size_t)(n0 + srow) * 32 + scol, Bs + wid * 1024);
    ldg_lds16(Wrb1 + (size_t)(n0 + srow + 16) * 32 + scol, Bs + wid * 1024 + 512);
    __syncthreads();
    f32x4 acc[4][4] = {};
    bf16x8 af[4], bfr[4];
#pragma unroll
    for (int i = 0; i < 4; i++) {
        af[i]  = *(const bf16x8*)(As + (wr * 64 + i * 16 + lrow) * 32 + lk8);
        bfr[i] = *(const bf16x8*)(Bs + (wc * 64 + i * 16 + lrow) * 32 + lk8);
    }
#pragma unroll
    for (int i = 0; i < 4; i++)
#pragma unroll
        for (int j = 0; j < 4; j++)
            acc[i][j] = __builtin_amdgcn_mfma_f32_16x16x32_bf16(af[i], bfr[j], acc[i][j], 0, 0, 0);

    int mtop = m0 + wr * 64 + (lane >> 4) * 4;
    int ntop = n0 + wc * 64 + lrow;
#pragma unroll
    for (int mi = 0; mi < 4; mi++) {
#pragma unroll
        for (int r = 0; r < 4; r++) {
            int m = mtop + mi * 16 + r;
#pragma unroll
            for (int ni = 0; ni < 4; ni++) {
                int n = ntop + ni * 16;
                float a = acc[mi][ni][r];
                if (n < 768) {
                    float v = fmaxf(a * scsh0[n] + scsh0[768 + n], 0.f);
                    h1[((size_t)b * 2050 + m + 1) * 768 + n] = (bf16)v;
                } else {
                    int o = n - 768;
                    float v = a * scshR[o] + scshR[768 + o];
                    res1[((size_t)b * 2048 + m) * 768 + o] = (bf16)v;
                }
            }
        }
    }
}

// ===================== QK^T*scale + banded rel-pos + mask — only alive tiles =====================
__device__ const int qk_ti[10] = {0, 0, 1, 1, 1, 2, 2, 2, 3, 3};
__device__ const int qk_tj[10] = {0, 1, 0, 1, 2, 1, 2, 3, 2, 3};

__global__ __launch_bounds__(256) void qkrel_k(
    const bf16* __restrict__ qkv, const float* __restrict__ relb, float* __restrict__ lg)
{
    int z = blockIdx.z, b = z >> 3, h = z & 7;
    int i0 = qk_ti[blockIdx.x] * 128, j0 = qk_tj[blockIdx.x] * 128;
    long long lgbase = (long long)z * 262144;
    const bf16* Aq = qkv + (size_t)b * 512 * 2304 + h * 96;
    const bf16* Bk = Aq + 768;
    __shared__ __align__(16) bf16 As[8192];
    __shared__ __align__(16) bf16 Bs[8192];
    int tid = threadIdx.x, wid = tid >> 6, lane = tid & 63;
    int wr = wid >> 1, wc = wid & 1;
    int lrow = lane & 15, lk8 = (lane >> 4) * 8;
    int srow = wid * 32 + (lane >> 2);
    int scol = (lane & 3) * 8;
    f32x4 acc[4][4] = {};

#define STAGE_QK(cur, kt) do { \
    ldg_lds16(Aq + (size_t)(i0 + srow) * 2304 + (kt) + scol, As + (cur) * 4096 + wid * 1024); \
    ldg_lds16(Aq + (size_t)(i0 + srow + 16) * 2304 + (kt) + scol, As + (cur) * 4096 + wid * 1024 + 512); \
    ldg_lds16(Bk + (size_t)(j0 + srow) * 2304 + (kt) + scol, Bs + (cur) * 4096 + wid * 1024); \
    ldg_lds16(Bk + (size_t)(j0 + srow + 16) * 2304 + (kt) + scol, Bs + (cur) * 4096 + wid * 1024 + 512); \
} while (0)

    STAGE_QK(0, 0);
    __syncthreads();
    for (int t = 0; t < 3; t++) {
        int cur = t & 1;
        if (t + 1 < 3) STAGE_QK(cur ^ 1, (t + 1) * 32);
        bf16x8 af[4], bfr[4];
#pragma unroll
        for (int i = 0; i < 4; i++) {
            af[i]  = *(const bf16x8*)(As + cur * 4096 + (wr * 64 + i * 16 + lrow) * 32 + lk8);
            bfr[i] = *(const bf16x8*)(Bs + cur * 4096 + (wc * 64 + i * 16 + lrow) * 32 + lk8);
        }
#pragma unroll
        for (int i = 0; i < 4; i++)
#pragma unroll
            for (int j = 0; j < 4; j++)
                acc[i][j] = __builtin_amdgcn_mfma_f32_16x16x32_bf16(af[i], bfr[j], acc[i][j], 0, 0, 0);
        __syncthreads();
    }
#undef STAGE_QK

    const float sc = 0.10206207261596577f;  // 1/sqrt(96)
    int itop = i0 + wr * 64 + (lane >> 4) * 4;
    int jtop = j0 + wc * 64 + lrow;
#pragma unroll
    for (int mi = 0; mi < 4; mi++) {
#pragma unroll
        for (int r = 0; r < 4; r++) {
            int i = itop + mi * 16 + r;
            const float* rrow = relb + ((long long)h * 4096 + b * 512 + i) * 256;
#pragma unroll
            for (int ni = 0; ni < 4; ni++) {
                int j = jtop + ni * 16;
                float v = acc[mi][ni][r] * sc;
                int idx = j - i + 99;
                v += (idx >= 0 && idx < 199) ? rrow[idx] : -1e8f;
                lg[lgbase + (long long)i * 512 + j] = v;
            }
        }
    }
}

// ===================== banded row softmax fp32 -> bf16 in place =====================
__global__ __launch_bounds__(256) void softmax_k(float* __restrict__ lg)
{
    __shared__ float red1[4];
    __shared__ float red2[4];
    size_t r = blockIdx.x;
    int i = (int)(r & 511);
    int jlo = i - 99; if (jlo < 0) jlo = 0;
    int jhi = i + 100; if (jhi > 512) jhi = 512;
    float* p = lg + r * 512;
    int tid = threadIdx.x;
    int j = jlo + tid;
    bool act = j < jhi;
    float v = act ? p[j] : -1e30f;
    float m = v;
#pragma unroll
    for (int off = 32; off; off >>= 1) m = fmaxf(m, __shfl_xor(m, off));
    if ((tid & 63) == 0) red1[tid >> 6] = m;
    __syncthreads();
    m = fmaxf(fmaxf(red1[0], red1[1]), fmaxf(red1[2], red1[3]));
    float e = act ? expf(v - m) : 0.f;
    float s = e;
#pragma unroll
    for (int off = 32; off; off >>= 1) s += __shfl_xor(s, off);
    if ((tid & 63) == 0) red2[tid >> 6] = s;
    __syncthreads();
    float inv = 1.f / (red2[0] + red2[1] + red2[2] + red2[3]);
    bf16* pb = (bf16*)p;
    if (act) pb[j] = (bf16)(e * inv);
#pragma unroll
    for (int c = tid; c < 512; c += 256)
        if (c < jlo || c >= jhi) pb[c] = (bf16)0.f;
}

// ===================== LayerNorm fp32 in (also zeroed after read), fp32 + bf16 out =====================
__global__ __launch_bounds__(256) void ln2_k(float* tmp,
                                             const float* __restrict__ g,
                                             const float* __restrict__ b,
                                             float* __restrict__ xf, bf16* __restrict__ xb)
{
    __shared__ float red1[4];
    __shared__ float red2[4];
    int r = blockIdx.x, tid = threadIdx.x;
    float* p = tmp + (size_t)r * 768;
    float x0 = p[tid], x1 = p[tid + 256], x2 = p[tid + 512];
    float s = x0 + x1 + x2;
#pragma unroll
    for (int off = 32; off; off >>= 1) s += __shfl_xor(s, off);
    if ((tid & 63) == 0) red1[tid >> 6] = s;
    __syncthreads();
    float mu = (red1[0] + red1[1] + red1[2] + red1[3]) * (1.f / 768.f);
    float d0 = x0 - mu, d1 = x1 - mu, d2 = x2 - mu;
    float sq = d0 * d0 + d1 * d1 + d2 * d2;
#pragma unroll
    for (int off = 32; off; off >>= 1) sq += __shfl_xor(sq, off);
    if ((tid & 63) == 0) red2[tid >> 6] = sq;
    __syncthreads();
    float rstd = rsqrtf((red2[0] + red2[1] + red2[2] + red2[3]) * (1.f / 768.f) + EPSF);
    float o0 = g[tid] * d0 * rstd + b[tid];
    float o1 = g[tid + 256] * d1 * rstd + b[tid + 256];
    float o2 = g[tid + 512] * d2 * rstd + b[tid + 512];
    // zero tmp for the next split-K atomic consumer
    p[tid] = 0.f; p[tid + 256] = 0.f; p[tid + 512] = 0.f;
    size_t base = (size_t)r * 768;
    xf[base + tid] = o0;       xb[base + tid] = (bf16)o0;
    xf[base + tid + 256] = o1; xb[base + tid + 256] = (bf16)o1;
    xf[base + tid + 512] = o2; xb[base + tid + 512] = (bf16)o2;
}

// ===================== small prep kernels =====================
struct BnPtrs { const float* bn[9]; const float* cb[9]; };
__global__ void bnprep9_k(BnPtrs p, float* __restrict__ scsh)
{
    int slot = blockIdx.y;
    int i = blockIdx.x * 256 + threadIdx.x;
    if (i >= 768) return;
    const float* bn = p.bn[slot];
    float g = bn[i], be = bn[768 + i], m = bn[1536 + i], v = bn[2304 + i];
    float sc = g * rsqrtf(v + EPSF);
    scsh[slot * 1536 + i] = sc;
    scsh[slot * 1536 + 768 + i] = (p.cb[slot][i] - m) * sc + be;
}

__global__ void zerof_k(float* __restrict__ p, long long n4)
{
    long long i = (long long)blockIdx.x * 256 + threadIdx.x;
    long long stride = (long long)gridDim.x * 256;
    float4 z = make_float4(0.f, 0.f, 0.f, 0.f);
    for (; i < n4; i += stride) ((float4*)p)[i] = z;
}

__global__ void xprep_k(const float* __restrict__ xr, bf16* __restrict__ xpadb)
{
    int i = blockIdx.x * 256 + threadIdx.x;
    if (i >= 262400) return;
    int c = i & 7, rb_ = i >> 3;
    int r = rb_ % 4100, b = rb_ / 4100;
    float v = (r >= 1 && r <= 4096) ? xr[((size_t)b * 4096 + r - 1) * 8 + c] : 0.f;
    xpadb[i] = (bf16)v;
}

__global__ void rb1wprep_k(const float* __restrict__ c1w, const float* __restrict__ rw,
                           bf16* __restrict__ Wrb1)
{
    int i = blockIdx.x * 256 + threadIdx.x;
    if (i >= 49152) return;
    int n = i >> 5, k = i & 31;
    int kq = k >> 3, c = k & 7;
    float v = 0.f;
    if (n < 768) { if (kq < 3) v = c1w[((size_t)n * 8 + c) * 3 + kq]; }
    else         { if (kq == 1) v = rw[(size_t)(n - 768) * 8 + c]; }
    Wrb1[i] = (bf16)v;
}

__global__ void rep3_k(const float* __restrict__ w, bf16* __restrict__ wr)
{
    long long i = (long long)blockIdx.x * 256 + threadIdx.x;
    if (i >= 1769472) return;
    int o = i / 2304, k = i - (long long)o * 2304;
    int kq = k / 768, ic = k - kq * 768;
    wr[i] = (bf16)w[((long long)o * 768 + ic) * 3 + kq];
}

__global__ void cast4_k(const float* __restrict__ s, bf16* __restrict__ d, int n4)
{
    int i = blockIdx.x * 256 + threadIdx.x;
    if (i >= n4) return;
    float4 v = ((const float4*)s)[i];
    bf16x4 o = {(bf16)v.x, (bf16)v.y, (bf16)v.z, (bf16)v.w};
    ((bf16x4*)d)[i] = o;
}

__global__ void layerprep_k(const float* __restrict__ wq, const float* __restrict__ wk,
                            const float* __restrict__ wv, const float* __restrict__ wo,
                            const float* __restrict__ rel,
                            const float* __restrict__ ff1, const float* __restrict__ ff2,
                            bf16* __restrict__ Wqkv, bf16* __restrict__ Wo,
                            bf16* __restrict__ Rel, bf16* __restrict__ F1, bf16* __restrict__ F2)
{
    long long i = (long long)blockIdx.x * 256 + threadIdx.x;
    const long long S0 = 1769472, S1 = 589824, S2 = 196608, S3 = 2359296;
    if (i < S0) {
        int n = i / 768, k = i - (long long)n * 768;
        int sel = n / 768, hq = n - sel * 768;
        int h = hq / 96, q = hq - h * 96;
        const float* src = sel == 0 ? wq : (sel == 1 ? wk : wv);
        Wqkv[i] = (bf16)src[((long long)h * 768 + k) * 96 + q];
    } else if (i < S0 + S1) {
        long long j = i - S0;
        int n = j / 768, kk = j - (long long)n * 768;
        Wo[j] = (bf16)wo[(long long)kk * 768 + n];
    } else if (i < S0 + S1 + S2) {
        long long j = i - S0 - S1;
        int h = j / 24576, rest = j - (long long)h * 24576;
        int rr = rest / 96, q = rest - rr * 96;
        Rel[j] = rr < 199 ? (bf16)rel[((long long)h * 199 + rr) * 96 + q] : (bf16)0.f;
    } else if (i < S0 + S1 + S2 + S3) {
        long long j = i - S0 - S1 - S2;
        F1[j] = (bf16)ff1[j];
    } else {
        long long j = i - S0 - S1 - S2 - S3;
        F2[j] = (bf16)ff2[j];
    }
}

// vt[z][q 0..127][t 0..511] = v part of qkv (rows 96..127 zero)
__global__ __launch_bounds__(256) void vt_k(const bf16* __restrict__ qkv, bf16* __restrict__ vt)
{
    int z = blockIdx.z, b = z >> 3, h = z & 7;
    int t0 = blockIdx.x * 32, q0 = blockIdx.y * 32;
    __shared__ bf16 sm[32][33];
    int tx = threadIdx.x & 31, ty = threadIdx.x >> 5;
#pragma unroll
    for (int s = 0; s < 4; s++) {
        int t = t0 + ty + s * 8, q = q0 + tx;
        sm[ty + s * 8][tx] = (q < 96) ? qkv[((size_t)b * 512 + t) * 2304 + 1536 + h * 96 + q]
                                      : (bf16)0.f;
    }
    __syncthreads();
#pragma unroll
    for (int s = 0; s < 4; s++) {
        int q = q0 + ty + s * 8;
        vt[((size_t)z * 128 + q) * 512 + t0 + tx] = sm[tx][ty + s * 8];
    }
}

// ===================== host launch =====================
extern "C" void kernel_launch(void* const* d_in, const int* in_sizes, int n_in,
                              void* d_out, int out_size, void* d_ws, size_t ws_size,
                              hipStream_t stream)
{
    const float* x_raw    = (const float*)d_in[0];
    const float* rb1_c1w  = (const float*)d_in[1];
    const float* rb1_c1b  = (const float*)d_in[2];
    const float* rb1_bn1  = (const float*)d_in[3];
    const float* rb1_c2w  = (const float*)d_in[4];
    const float* rb1_c2b  = (const float*)d_in[5];
    const float* rb1_bn2  = (const float*)d_in[6];
    const float* rb1_rw   = (const float*)d_in[7];
    const float* rb1_rb   = (const float*)d_in[8];
    const float* rb1_bnr  = (const float*)d_in[9];
    const float* rb23_c1w = (const float*)d_in[10];
    const float* rb23_c1b = (const float*)d_in[11];
    const float* rb23_bn1 = (const float*)d_in[12];
    const float* rb23_c2w = (const float*)d_in[13];
    const float* rb23_c2b = (const float*)d_in[14];
    const float* rb23_bn2 = (const float*)d_in[15];
    const float* rb23_rw  = (const float*)d_in[16];
    const float* rb23_rb  = (const float*)d_in[17];
    const float* rb23_bnr = (const float*)d_in[18];
    const float* w_in_w   = (const float*)d_in[19];
    const float* w_in_b   = (const float*)d_in[20];
    const float* wq       = (const float*)d_in[21];
    const float* wk       = (const float*)d_in[22];
    const float* wv       = (const float*)d_in[23];
    const float* wo       = (const float*)d_in[24];
    const float* rel_emb  = (const float*)d_in[25];
    const float* ln1_g    = (const float*)d_in[26];
    const float* ln1_b    = (const float*)d_in[27];
    const float* ln2_g    = (const float*)d_in[28];
    const float* ln2_b    = (const float*)d_in[29];
    const float* ff1_w    = (const float*)d_in[30];
    const float* ff1_b    = (const float*)d_in[31];
    const float* ff2_w    = (const float*)d_in[32];
    const float* ff2_b    = (const float*)d_in[33];
    const float* w_out_w  = (const float*)d_in[34];
    const float* w_out_b  = (const float*)d_in[35];
    float* out = (float*)d_out;

    char* W = (char*)d_ws;
    bf16*  h1buf  = (bf16*)(W + 0);
    bf16*  resbuf = (bf16*)(W + 26000000);
    bf16*  xbuf   = (bf16*)(W + 52000000);
    float* lg     = (float*)(W + 0);          // transformer phase
    bf16*  wc3    = (bf16*)(W + 78000000);
    bf16*  wc1    = (bf16*)(W + 82000000);
    bf16*  xpadb  = (bf16*)(W + 83300000);
    bf16*  Wrb1   = (bf16*)(W + 83900000);
    float* scsh   = (float*)(W + 84000000);
    float* xf     = (float*)(W + 85000000);
    bf16*  xb     = (bf16*)(W + 98000000);
    bf16*  qkv    = (bf16*)(W + 105000000);
    bf16*  vt     = (bf16*)(W + 124000000);
    float* relb   = (float*)(W + 133000000);
    bf16*  ffh    = (bf16*)(W + 133000000);
    bf16*  atno   = (bf16*)(W + 167000000);
    float* tmp    = (float*)(W + 174000000);
    bf16*  Wqkv   = (bf16*)(W + 187000000);
    bf16*  Wo     = (bf16*)(W + 191000000);
    bf16*  F1     = (bf16*)(W + 193000000);
    bf16*  F2     = (bf16*)(W + 198000000);
    bf16*  Relp   = (bf16*)(W + 203000000);
    bf16*  Wout   = (bf16*)(W + 204000000);
    bf16*  Winw   = (bf16*)(W + 206000000);

    // ---- BN fold (one launch) ----
    BnPtrs bp;
    bp.bn[0] = rb1_bn1; bp.cb[0] = rb1_c1b;
    bp.bn[1] = rb1_bnr; bp.cb[1] = rb1_rb;
    bp.bn[2] = rb1_bn2; bp.cb[2] = rb1_c2b;
    bp.bn[3] = rb23_bn1; bp.cb[3] = rb23_c1b;
    bp.bn[4] = rb23_bnr; bp.cb[4] = rb23_rb;
    bp.bn[5] = rb23_bn2; bp.cb[5] = rb23_c2b;
    bp.bn[6] = rb23_bn1 + 3072; bp.cb[6] = rb23_c1b + 768;
    bp.bn[7] = rb23_bnr + 3072; bp.cb[7] = rb23_rb + 768;
    bp.bn[8] = rb23_bn2 + 3072; bp.cb[8] = rb23_c2b + 768;
    bnprep9_k<<<dim3(3, 9), 256, 0, stream>>>(bp, scsh);

    // ---- rb1 front as GEMM ----
    xprep_k<<<1025, 256, 0, stream>>>(x_raw, xpadb);
    rb1wprep_k<<<192, 256, 0, stream>>>(rb1_c1w, rb1_rw, Wrb1);
    rb1gemm_k<<<dim3(12, 16, 8), 256, 0, stream>>>(xpadb, Wrb1, scsh, scsh + 1536, h1buf, resbuf);

    // ---- conv stack, t-major bf16, T 2048->1024->512 ----
    rep3_k<<<6912, 256, 0, stream>>>(rb1_c2w, wc3);
    conv_k<true, true><<<dim3(6, 16, 8), 256, 0, stream>>>(
        h1buf, wc3, scsh + 2 * 1536, resbuf, xbuf, 2304, 1, 0,
        (long long)2050 * 768, (long long)2050 * 768, 1, (long long)2048 * 768, 2048);
    // rb2
    rep3_k<<<6912, 256, 0, stream>>>(rb23_c1w, wc3);
    conv_k<false, true><<<dim3(6, 8, 8), 256, 0, stream>>>(
        xbuf, wc3, scsh + 3 * 1536, nullptr, h1buf, 2304, 2, 0,
        (long long)2050 * 768, (long long)1026 * 768, 1, 0, 1024);
    cast4_k<<<576, 256, 0, stream>>>(rb23_rw, wc1, 147456);
    conv_k<false, false><<<dim3(6, 8, 8), 256, 0, stream>>>(
        xbuf, wc1, scsh + 4 * 1536, nullptr, resbuf, 768, 2, 1,
        (long long)2050 * 768, (long long)1024 * 768, 0, 0, 0);
    rep3_k<<<6912, 256, 0, stream>>>(rb23_c2w, wc3);
    conv_k<true, true><<<dim3(6, 8, 8), 256, 0, stream>>>(
        h1buf, wc3, scsh + 5 * 1536, resbuf, xbuf, 2304, 1, 0,
        (long long)1026 * 768, (long long)1026 * 768, 1, (long long)1024 * 768, 1024);
    // rb3
    rep3_k<<<6912, 256, 0, stream>>>(rb23_c1w + 1769472, wc3);
    conv_k<false, true><<<dim3(6, 4, 8), 256, 0, stream>>>(
        xbuf, wc3, scsh + 6 * 1536, nullptr, h1buf, 2304, 2, 0,
        (long long)1026 * 768, (long long)514 * 768, 1, 0, 512);
    cast4_k<<<576, 256, 0, stream>>>(rb23_rw + 589824, wc1, 147456);
    conv_k<false, false><<<dim3(6, 4, 8), 256, 0, stream>>>(
        xbuf, wc1, scsh + 7 * 1536, nullptr, resbuf, 768, 2, 1,
        (long long)1026 * 768, (long long)512 * 768, 0, 0, 0);
    rep3_k<<<6912, 256, 0, stream>>>(rb23_c2w + 1769472, wc3);
    conv_k<true, true><<<dim3(6, 4, 8), 256, 0, stream>>>(
        h1buf, wc3, scsh + 8 * 1536, resbuf, xbuf, 2304, 1, 0,
        (long long)514 * 768, (long long)512 * 768, 0, (long long)512 * 768, 0);
    // xbuf = x3 [4096][768] bf16 = transformer input

    // ---- transformer ----
    cast4_k<<<576, 256, 0, stream>>>(w_in_w, Winw, 147456);
    cast4_k<<<768, 256, 0, stream>>>(w_out_w, Wout, 196608);
    zerof_k<<<2048, 256, 0, stream>>>(tmp, 786432);  // prime tmp for first atomic consumer
    mgemm_k<true, false, false, true, true, false><<<dim3(6, 32, 1), 256, 0, stream>>>(
        xbuf, Winw, w_in_b, nullptr, xf, xb, 768, 768, 768, 768, 768,
        1, 0, 0, 0, 0, 0, 0, 1);

    for (int l = 0; l < 6; l++) {
        layerprep_k<<<28416, 256, 0, stream>>>(
            wq + (size_t)l * 589824, wk + (size_t)l * 589824, wv + (size_t)l * 589824,
            wo + (size_t)l * 589824, rel_emb + (size_t)l * 152832,
            ff1_w + (size_t)l * 2359296, ff2_w + (size_t)l * 2359296,
            Wqkv, Wo, Relp, F1, F2);
        // fused QKV
        mgemm_k<false, false, false, false, true, false><<<dim3(18, 32, 1), 256, 0, stream>>>(
            xb, Wqkv, nullptr, nullptr, nullptr, qkv, 768, 768, 768, 2304, 2304,
            1, 0, 0, 0, 0, 0, 0, 1);
        vt_k<<<dim3(16, 4, 64), 256, 0, stream>>>(qkv, vt);
        // rel logits (padded N=256)
        mgemm_k<false, false, false, true, false, false><<<dim3(2, 32, 8), 256, 0, stream>>>(
            qkv, Relp, nullptr, nullptr, relb, nullptr, 96, 2304, 96, 256, 256,
            1, 96, 0, 24576, 0, 1048576, 0, 1);
        qkrel_k<<<dim3(10, 1, 64), 256, 0, stream>>>(qkv, relb, lg);
        softmax_k<<<32768, 256, 0, stream>>>(lg);
        // PV (band-restricted K)
        mgemm_k<false, false, false, false, true, true><<<dim3(1, 4, 64), 256, 0, stream>>>(
            (const bf16*)lg, vt, nullptr, nullptr, nullptr, atno, 512, 1024, 512, 768, 96,
            8, 4194304, 524288, 524288, 65536, 393216, 96, 1);
        // out-proj + residual (split-K 2, atomic into pre-zeroed tmp)
        mgemm_k<false, true, false, true, false, false, true><<<dim3(6, 32, 2), 256, 0, stream>>>(
            atno, Wo, nullptr, xf, tmp, nullptr, 768, 768, 768, 768, 768,
            1, 0, 0, 0, 0, 0, 0, 2);
        ln2_k<<<4096, 256, 0, stream>>>(tmp, ln1_g + l * 768, ln1_b + l * 768, xf, xb);
        // FF
        mgemm_k<true, false, true, false, true, false><<<dim3(24, 32, 1), 256, 0, stream>>>(
            xb, F1, ff1_b + l * 3072, nullptr, nullptr, ffh, 768, 768, 768, 3072, 3072,
            1, 0, 0, 0, 0, 0, 0, 1);
        // FF2 (split-K 4, atomic into tmp zeroed by previous ln2_k)
        mgemm_k<true, true, false, true, false, false, true><<<dim3(6, 32, 4), 256, 0, stream>>>(
            ffh, F2, ff2_b + l * 768, xf, tmp, nullptr, 3072, 3072, 3072, 768, 768,
            1, 0, 0, 0, 0, 0, 0, 4);
        ln2_k<<<4096, 256, 0, stream>>>(tmp, ln2_g + l * 768, ln2_b + l * 768, xf, xb);
    }

    // output head (split-K 2, atomic into zeroed d_out)
    zerof_k<<<2048, 256, 0, stream>>>(out, 1048576);
    mgemm_k<true, false, false, true, false, false, true><<<dim3(8, 32, 2), 256, 0, stream>>>(
        xb, Wout, w_out_b, nullptr, out, nullptr, 768, 768, 768, 1024, 1024,
        1, 0, 0, 0, 0, 0, 0, 2);
}